// Round 10
// baseline (1192.891 us; speedup 1.0000x reference)
//
#include <hip/hip_runtime.h>
#include <math.h>

#define NN 100000
#define EE 800000
#define DH 128
#define NL 16
#define GEMM_GRID 1563
#define SG_GRID 782      // ceil(100000 / 128) for 8-wave blocks
#define NSLOT 32

typedef __bf16 bf16x8 __attribute__((ext_vector_type(8)));
typedef float f32x4 __attribute__((ext_vector_type(4)));

// ---------------- CSR build ----------------
__global__ void k_hist(const int* __restrict__ row, int* __restrict__ cnt) {
    int e = blockIdx.x * 256 + threadIdx.x;
    if (e < EE) atomicAdd(&cnt[__builtin_nontemporal_load(&row[e])], 1);
}

__global__ void k_scan1(const int* __restrict__ cnt, int* __restrict__ rp, int* __restrict__ part) {
    __shared__ int buf[512];
    int tid = threadIdx.x;
    int i = blockIdx.x * 512 + tid;
    int v = (i < NN) ? cnt[i] : 0;
    buf[tid] = v;
    __syncthreads();
    for (int off = 1; off < 512; off <<= 1) {
        int x = (tid >= off) ? buf[tid - off] : 0;
        __syncthreads();
        buf[tid] += x;
        __syncthreads();
    }
    if (i < NN) rp[i] = buf[tid] - v;
    if (tid == 511) part[blockIdx.x] = buf[511];
}

__global__ void k_scan2(int* __restrict__ part, int nparts) {
    __shared__ int buf[256];
    int tid = threadIdx.x;
    int v = (tid < nparts) ? part[tid] : 0;
    buf[tid] = v;
    __syncthreads();
    for (int off = 1; off < 256; off <<= 1) {
        int x = (tid >= off) ? buf[tid - off] : 0;
        __syncthreads();
        buf[tid] += x;
        __syncthreads();
    }
    if (tid < nparts) part[tid] = buf[tid] - v;
}

__global__ void k_scan3(int* __restrict__ rp, const int* __restrict__ part) {
    int i = blockIdx.x * 512 + threadIdx.x;
    if (i < NN) rp[i] += part[blockIdx.x];
    if (i == 0) rp[NN] = EE;
}

// ---------------- degree-sort permutation (counting sort, 64 bins, DESCENDING for LPT) ----------------
__global__ void k_dhist(const int* __restrict__ cnt, int* __restrict__ dbin) {
    __shared__ int lb[64];
    int tid = threadIdx.x;
    if (tid < 64) lb[tid] = 0;
    __syncthreads();
    int i = blockIdx.x * 256 + tid;
    if (i < NN) {
        int d = cnt[i];
        if (d > 63) d = 63;
        atomicAdd(&lb[63 - d], 1);
    }
    __syncthreads();
    if (tid < 64 && lb[tid]) atomicAdd(&dbin[tid], lb[tid]);
}

__global__ void k_pscan(const int* __restrict__ dbin, int* __restrict__ dpre) {
    if (threadIdx.x == 0) {
        int s = 0;
        for (int i = 0; i < 64; ++i) { dpre[i] = s; s += dbin[i]; }
    }
}

__global__ void k_pscatter(const int* __restrict__ cnt, const int* __restrict__ dpre,
                           int* __restrict__ dfil, int* __restrict__ perm) {
    __shared__ int lcnt[64], lbase[64];
    int tid = threadIdx.x;
    if (tid < 64) lcnt[tid] = 0;
    __syncthreads();
    int i = blockIdx.x * 256 + tid;
    int b = 0, loc = 0;
    bool ok = (i < NN);
    if (ok) {
        int d = cnt[i];
        if (d > 63) d = 63;
        b = 63 - d;
        loc = atomicAdd(&lcnt[b], 1);
    }
    __syncthreads();
    if (tid < 64 && lcnt[tid]) lbase[tid] = atomicAdd(&dfil[tid], lcnt[tid]);
    __syncthreads();
    if (ok) perm[dpre[b] + lbase[b] + loc] = i;
}

// iperm[perm[i]] = i; cnt2[i] = degree of i-th sorted node (for permuted-space rp)
__global__ void k_iperm(const int* __restrict__ perm, const int* __restrict__ cnt,
                        int* __restrict__ iperm, int* __restrict__ cnt2) {
    int i = blockIdx.x * 256 + threadIdx.x;
    if (i < NN) {
        int p = perm[i];
        iperm[p] = i;
        cnt2[i] = cnt[p];
    }
}

// ---------------- k_fill: single pass, NONTEMPORAL stores ----------------
// R9 falsified the XCD-window model (WRITE still 48.6MB): the blockIdx->XCD
// mapping decays under this kernel's load imbalance. New hypothesis: the 7.6x
// write amplification is write-ALLOCATE (each 8B scatter fetches + partially
// fills a 64B line that gets evicted early). nt stores stream past allocation;
// nt loads on the edge streams stop them evicting partial ep lines.
// WRITE_SIZE is the test: <12MB if right, ~50MB if wrong.
__global__ void k_fill(const int* __restrict__ row, const int* __restrict__ col,
                       const float* __restrict__ w, const int* __restrict__ rp,
                       const int* __restrict__ iperm,
                       int* __restrict__ fil, int2* __restrict__ ep) {
    int e = blockIdx.x * 256 + threadIdx.x;
    if (e >= EE) return;
    int r = iperm[__builtin_nontemporal_load(&row[e])];
    int c = iperm[__builtin_nontemporal_load(&col[e])];
    float wv = 0.9f * __builtin_nontemporal_load(&w[e]);
    int pos = rp[r] + atomicAdd(&fil[r], 1);
    unsigned long long v = (unsigned long long)(unsigned)c |
                           ((unsigned long long)(unsigned)__float_as_int(wv) << 32);
    __builtin_nontemporal_store(v, (unsigned long long*)&ep[pos]);
}

// ---------------- weight prep: split hi/lo bf16 + swizzle to MFMA fragment order ----------------
__global__ void k_prep_w(const float* __restrict__ convW, const float* __restrict__ Win,
                         __bf16* __restrict__ Bhi, __bf16* __restrict__ Blo) {
    int l = blockIdx.x;
    const float* W;
    float beta, ob;
    if (l < NL) {
        beta = logf(0.5f / (float)(l + 1) + 1.0f);
        ob = 1.0f - beta;
        W = convW + (size_t)l * DH * DH;
    } else {
        beta = 1.0f;
        ob = 0.0f;
        W = Win;
    }
    __bf16* bh = Bhi + (size_t)l * DH * DH;
    __bf16* bl = Blo + (size_t)l * DH * DH;
    for (int i = threadIdx.x; i < DH * DH; i += 256) {
        int k = i >> 7, j = i & 127;
        float v = beta * W[i] + ((k == j) ? ob : 0.f);
        __bf16 hv = (__bf16)v;
        int t = j >> 4, n = j & 15, ks = k >> 5, quad = (k >> 3) & 3, e = k & 7;
        int off = ((t * 4 + ks) * 64 + quad * 16 + n) * 8 + e;
        bh[off] = hv;
        bl[off] = (__bf16)(v - (float)hv);
    }
}

__global__ void k_prep_out(const float* __restrict__ Wout, __bf16* __restrict__ Bhi, __bf16* __restrict__ Blo) {
    for (int i = threadIdx.x; i < DH * 48; i += 256) {
        int k = i / 48, j = i % 48;
        float v = (j < 40) ? Wout[k * 40 + j] : 0.f;
        __bf16 hv = (__bf16)v;
        int t = j >> 4, n = j & 15, ks = k >> 5, quad = (k >> 3) & 3, e = k & 7;
        int off = ((t * 4 + ks) * 64 + quad * 16 + n) * 8 + e;
        Bhi[off] = hv;
        Blo[off] = (__bf16)(v - (float)hv);
    }
}

__device__ inline void split8(const float* p, bf16x8& hi, bf16x8& lo) {
    f32x4 v0 = *(const f32x4*)p;
    f32x4 v1 = *(const f32x4*)(p + 4);
#pragma unroll
    for (int j = 0; j < 4; ++j) {
        __bf16 h0 = (__bf16)v0[j];
        hi[j] = h0;
        lo[j] = (__bf16)(v0[j] - (float)h0);
        __bf16 h1 = (__bf16)v1[j];
        hi[4 + j] = h1;
        lo[4 + j] = (__bf16)(v1[j] - (float)h1);
    }
}

#define MFMA(a, b, c) __builtin_amdgcn_mfma_f32_16x16x32_bf16(a, b, c, 0, 0, 0)

// ---------------- int8 group quantization helpers ----------------
__device__ inline float dec_scale(unsigned int sc4, int ks) {
    return __uint_as_float(((sc4 >> (8 * ks)) & 0xffu) << 23);
}

#define DEC_DW(dw, wsv, a0, a1, a2, a3)                         \
    {                                                           \
        a0 = fmaf(wsv, (float)((dw)&0xffu), a0);                \
        a1 = fmaf(wsv, (float)(((dw) >> 8) & 0xffu), a1);       \
        a2 = fmaf(wsv, (float)(((dw) >> 16) & 0xffu), a2);      \
        a3 = fmaf(wsv, (float)((dw) >> 24), a3);                \
    }

#define EDGE_FMA(S4, W, RA, RB)                                       \
    {                                                                 \
        float _w = (W);                                               \
        float _w0 = _w * dec_scale(S4, 0);                            \
        float _w1 = _w * dec_scale(S4, 1);                            \
        float _w2 = _w * dec_scale(S4, 2);                            \
        float _w3 = _w * dec_scale(S4, 3);                            \
        sw0 += _w0; sw1 += _w1; sw2 += _w2; sw3 += _w3;               \
        DEC_DW((RA).x, _w0, acc[0][0], acc[0][1], acc[0][2], acc[0][3]); \
        DEC_DW((RA).y, _w0, acc[0][4], acc[0][5], acc[0][6], acc[0][7]); \
        DEC_DW((RA).z, _w1, acc[1][0], acc[1][1], acc[1][2], acc[1][3]); \
        DEC_DW((RA).w, _w1, acc[1][4], acc[1][5], acc[1][6], acc[1][7]); \
        DEC_DW((RB).x, _w2, acc[2][0], acc[2][1], acc[2][2], acc[2][3]); \
        DEC_DW((RB).y, _w2, acc[2][4], acc[2][5], acc[2][6], acc[2][7]); \
        DEC_DW((RB).z, _w3, acc[3][0], acc[3][1], acc[3][2], acc[3][3]); \
        DEC_DW((RB).w, _w3, acc[3][4], acc[3][5], acc[3][6], acc[3][7]); \
    }

// ---------------- FUSED SpMM + mix + layer GEMM; emits a8+asc (int8) ----------------
__global__ __launch_bounds__(512, 4) void k_spmm_gemm(const unsigned char* __restrict__ hin8,
                                                      const unsigned char* __restrict__ hinsc,
                                                      const unsigned char* __restrict__ x08,
                                                      const unsigned char* __restrict__ x0sc,
                                                      const int* __restrict__ rp, const int2* __restrict__ ep,
                                                      unsigned char* __restrict__ a8, unsigned char* __restrict__ asc,
                                                      const __bf16* __restrict__ Bhi, const __bf16* __restrict__ Blo,
                                                      float* __restrict__ stats32) {
    __shared__ __bf16 Bs[2 * DH * DH];  // [hi|lo] in MFMA fragment order
    __shared__ float red[2][8][DH];
    int tid = threadIdx.x;
    {
        const f32x4* sh = (const f32x4*)Bhi;
        const f32x4* sl = (const f32x4*)Blo;
        f32x4* dh = (f32x4*)Bs;
        f32x4* dl = (f32x4*)(Bs + DH * DH);
#pragma unroll
        for (int i = 0; i < 4; ++i) {
            dh[tid + i * 512] = sh[tid + i * 512];
            dl[tid + i * 512] = sl[tid + i * 512];
        }
    }
    // no sync yet: gather phase doesn't touch Bs; sync sits right before MFMA.

    int wave = tid >> 6, lane = tid & 63;
    int n = lane & 15, quad = lane >> 4;
    int r0 = blockIdx.x * 128 + wave * 16;
    int node = r0 + n;
    int nc = (node < NN) ? node : (NN - 1);

    float acc[4][8];
#pragma unroll
    for (int ks = 0; ks < 4; ++ks)
#pragma unroll
        for (int c = 0; c < 8; ++c) acc[ks][c] = 0.f;
    float sw0 = 0.f, sw1 = 0.f, sw2 = 0.f, sw3 = 0.f;

    // x0 self-term loads
    unsigned xs4 = *(const unsigned*)&x0sc[(size_t)nc * 4];
    const unsigned char* xb = x08 + (size_t)nc * 128 + quad * 16;
    uint4 xa = *(const uint4*)xb;
    uint4 xc = *(const uint4*)(xb + 64);

    int s = 0, e = 0;
    if (node < NN) { s = rp[node]; e = rp[node + 1]; }
    int cnt = e - s;
    int npairs = cnt >> 1;

    const unsigned char* hb = hin8 + quad * 16;

    int2 cP0, cP1, fP0, fP1;
    unsigned cS0, cS1;
    uint4 cA0, cB0, cA1, cB1;
    if (npairs > 0) {
        cP0 = ep[s]; cP1 = ep[s + 1];
        cS0 = *(const unsigned*)&hinsc[(size_t)cP0.x * 4];
        cS1 = *(const unsigned*)&hinsc[(size_t)cP1.x * 4];
        const unsigned char* b0 = hb + (size_t)cP0.x * 128;
        const unsigned char* b1 = hb + (size_t)cP1.x * 128;
        cA0 = *(const uint4*)b0; cB0 = *(const uint4*)(b0 + 64);
        cA1 = *(const uint4*)b1; cB1 = *(const uint4*)(b1 + 64);
        int jf = s + 2; if (jf > EE - 2) jf = EE - 2;
        fP0 = ep[jf]; fP1 = ep[jf + 1];
    }

    EDGE_FMA(xs4, 0.1f, xa, xc);   // weight 0.1 on x0 (alpha mix)

    int j = s;
    for (int it = 0; it < npairs; ++it) {
        int j2 = j + 4; if (j2 > EE - 2) j2 = EE - 2;
        int2 eN0 = ep[j2], eN1 = ep[j2 + 1];
        unsigned tS0 = *(const unsigned*)&hinsc[(size_t)fP0.x * 4];
        unsigned tS1 = *(const unsigned*)&hinsc[(size_t)fP1.x * 4];
        const unsigned char* b0 = hb + (size_t)fP0.x * 128;
        const unsigned char* b1 = hb + (size_t)fP1.x * 128;
        uint4 tA0 = *(const uint4*)b0, tB0 = *(const uint4*)(b0 + 64);
        uint4 tA1 = *(const uint4*)b1, tB1 = *(const uint4*)(b1 + 64);
        EDGE_FMA(cS0, __int_as_float(cP0.y), cA0, cB0);
        EDGE_FMA(cS1, __int_as_float(cP1.y), cA1, cB1);
        cP0 = fP0; cP1 = fP1; fP0 = eN0; fP1 = eN1;
        cS0 = tS0; cS1 = tS1;
        cA0 = tA0; cB0 = tB0; cA1 = tA1; cB1 = tB1;
        j += 2;
    }
    if (cnt & 1) {
        int2 pe = ep[e - 1];
        unsigned s4 = *(const unsigned*)&hinsc[(size_t)pe.x * 4];
        const unsigned char* bp = hb + (size_t)pe.x * 128;
        uint4 ra = *(const uint4*)bp, rb = *(const uint4*)(bp + 64);
        EDGE_FMA(s4, __int_as_float(pe.y), ra, rb);
    }

    // bias correction (u8 -> u8-128) + bf16 A fragments
    bf16x8 av[4];
    {
        float sws[4] = {sw0, sw1, sw2, sw3};
#pragma unroll
        for (int ks = 0; ks < 4; ++ks)
#pragma unroll
            for (int c = 0; c < 8; ++c)
                av[ks][c] = (__bf16)(acc[ks][c] - 128.0f * sws[ks]);
    }

    __syncthreads();  // Bs staging complete across all waves

    f32x4 gacc[8];
#pragma unroll
    for (int t = 0; t < 8; ++t) gacc[t] = (f32x4){0.f, 0.f, 0.f, 0.f};

#pragma unroll
    for (int ks = 0; ks < 4; ++ks) {
#pragma unroll
        for (int t = 0; t < 8; ++t) {
            int base = ((t * 4 + ks) * 64 + lane) * 8;
            bf16x8 bh = *(const bf16x8*)&Bs[base];
            bf16x8 bl = *(const bf16x8*)&Bs[DH * DH + base];
            gacc[t] = MFMA(av[ks], bh, gacc[t]);
            gacc[t] = MFMA(av[ks], bl, gacc[t]);
        }
    }

    // ---- int8 quantize epilogue: group (row, 32-col) max over the 16 n-lanes ----
    float m[4][4];
#pragma unroll
    for (int r = 0; r < 4; ++r)
#pragma unroll
        for (int g = 0; g < 4; ++g)
            m[r][g] = fmaxf(fabsf(gacc[2 * g][r]), fabsf(gacc[2 * g + 1][r]));
#pragma unroll
    for (int d = 1; d <= 8; d <<= 1)
#pragma unroll
        for (int r = 0; r < 4; ++r)
#pragma unroll
            for (int g = 0; g < 4; ++g)
                m[r][g] = fmaxf(m[r][g], __shfl_xor(m[r][g], d));
    unsigned ebu[4];
    float sinv[4][4];
#pragma unroll
    for (int r = 0; r < 4; ++r) {
        unsigned u32 = 0;
#pragma unroll
        for (int g = 0; g < 4; ++g) {
            unsigned em = (__float_as_uint(m[r][g]) >> 23) & 0xffu;
            unsigned eb;
            float si;
            if (em < 7) { eb = 0; si = 0.f; }
            else { eb = em - 6; si = __uint_as_float((254 - eb) << 23); }
            u32 |= eb << (8 * g);
            sinv[r][g] = si;
        }
        ebu[r] = u32;
    }

#pragma unroll
    for (int t = 0; t < 8; ++t) {
        float sm = 0.f, qq = 0.f;
        int wb = (t >> 2) * 64 + ((((t & 1) << 1) | (n >> 3))) * 16 + ((t >> 1) & 1) * 8 + (n & 7);
#pragma unroll
        for (int r = 0; r < 4; ++r) {
            int row = r0 + quad * 4 + r;
            float v = gacc[t][r];
            if (row < NN) {
                unsigned qv = (unsigned)rintf(fminf(fmaf(v, sinv[r][t >> 1], 128.f), 255.f));
                a8[(size_t)row * 128 + wb] = (unsigned char)qv;
                sm += v;       // stats from EXACT values
                qq += v * v;
            }
        }
        sm += __shfl_xor(sm, 16); sm += __shfl_xor(sm, 32);
        qq += __shfl_xor(qq, 16); qq += __shfl_xor(qq, 32);
        if (quad == 0) {
            red[0][wave][t * 16 + n] = sm;
            red[1][wave][t * 16 + n] = qq;
        }
    }
    if (n == 0) {
#pragma unroll
        for (int r = 0; r < 4; ++r) {
            int row = r0 + quad * 4 + r;
            if (row < NN) *(unsigned*)&asc[(size_t)row * 4] = ebu[r];
        }
    }
    __syncthreads();
    if (tid < 256) {
        int which = tid >> 7, jj = tid & 127;
        float tot = 0.f;
#pragma unroll
        for (int w = 0; w < 8; ++w) tot += red[which][w][jj];
        atomicAdd(&stats32[(size_t)(blockIdx.x & (NSLOT - 1)) * 256 + tid], tot);
    }
}

// ---------------- input GEMM + fused int8 encode: x0/x08/xsc from X[perm[i]] ----------------
__global__ __launch_bounds__(512, 4) void k_lin_in(const float* __restrict__ X, const int* __restrict__ perm,
                                                   const __bf16* __restrict__ Bhi, const __bf16* __restrict__ Blo,
                                                   const float* __restrict__ bin, __bf16* __restrict__ x0,
                                                   unsigned char* __restrict__ x08, unsigned char* __restrict__ xsc) {
    __shared__ __bf16 Bs[2 * DH * DH];
    int tid = threadIdx.x;
    {
        const f32x4* sh = (const f32x4*)Bhi;
        const f32x4* sl = (const f32x4*)Blo;
        f32x4* dh = (f32x4*)Bs;
        f32x4* dl = (f32x4*)(Bs + DH * DH);
#pragma unroll
        for (int i = 0; i < 4; ++i) {
            dh[tid + i * 512] = sh[tid + i * 512];
            dl[tid + i * 512] = sl[tid + i * 512];
        }
    }
    __syncthreads();

    int wave = tid >> 6, lane = tid & 63;
    int n = lane & 15, quad = lane >> 4;
    int r0 = blockIdx.x * 128 + wave * 16;
    int arow = r0 + n;
    if (arow > NN - 1) arow = NN - 1;
    const float* pa = X + (size_t)perm[arow] * DH + quad * 8;

    f32x4 acc[8];
#pragma unroll
    for (int t = 0; t < 8; ++t) acc[t] = (f32x4){0.f, 0.f, 0.f, 0.f};

#pragma unroll
    for (int ks = 0; ks < 4; ++ks) {
        bf16x8 ah, al;
        split8(pa + ks * 32, ah, al);
#pragma unroll
        for (int t = 0; t < 8; ++t) {
            int base = ((t * 4 + ks) * 64 + lane) * 8;
            bf16x8 bh = *(const bf16x8*)&Bs[base];
            bf16x8 bl = *(const bf16x8*)&Bs[DH * DH + base];
            acc[t] = MFMA(ah, bh, acc[t]);
            acc[t] = MFMA(al, bh, acc[t]);
            acc[t] = MFMA(ah, bl, acc[t]);
        }
    }

#pragma unroll
    for (int t = 0; t < 8; ++t) {
        float bj = bin[t * 16 + n];
#pragma unroll
        for (int r = 0; r < 4; ++r) {
            float v = fmaxf(acc[t][r] + bj, 0.f);
            acc[t][r] = v;
            int row = r0 + quad * 4 + r;
            if (row < NN) x0[(size_t)row * DH + t * 16 + n] = (__bf16)v;
        }
    }

    // fused int8 encode (same pattern as spmm epilogue; bf16 rounding first to
    // match what the old k_cvt8 read back)
    float m[4][4];
#pragma unroll
    for (int r = 0; r < 4; ++r)
#pragma unroll
        for (int g = 0; g < 4; ++g) {
            float v0 = (float)(__bf16)acc[2 * g][r];
            float v1 = (float)(__bf16)acc[2 * g + 1][r];
            m[r][g] = fmaxf(fabsf(v0), fabsf(v1));
        }
#pragma unroll
    for (int d = 1; d <= 8; d <<= 1)
#pragma unroll
        for (int r = 0; r < 4; ++r)
#pragma unroll
            for (int g = 0; g < 4; ++g)
                m[r][g] = fmaxf(m[r][g], __shfl_xor(m[r][g], d));
    unsigned ebu[4];
    float sinv[4][4];
#pragma unroll
    for (int r = 0; r < 4; ++r) {
        unsigned u32 = 0;
#pragma unroll
        for (int g = 0; g < 4; ++g) {
            unsigned em = (__float_as_uint(m[r][g]) >> 23) & 0xffu;
            unsigned eb;
            float si;
            if (em < 7) { eb = 0; si = 0.f; }
            else { eb = em - 6; si = __uint_as_float((254 - eb) << 23); }
            u32 |= eb << (8 * g);
            sinv[r][g] = si;
        }
        ebu[r] = u32;
    }
#pragma unroll
    for (int t = 0; t < 8; ++t) {
        int wb = (t >> 2) * 64 + ((((t & 1) << 1) | (n >> 3))) * 16 + ((t >> 1) & 1) * 8 + (n & 7);
#pragma unroll
        for (int r = 0; r < 4; ++r) {
            int row = r0 + quad * 4 + r;
            if (row < NN) {
                float v = (float)(__bf16)acc[t][r];
                unsigned qv = (unsigned)rintf(fminf(fmaf(v, sinv[r][t >> 1], 128.f), 255.f));
                x08[(size_t)row * 128 + wb] = (unsigned char)qv;
            }
        }
    }
    if (n == 0) {
#pragma unroll
        for (int r = 0; r < 4; ++r) {
            int row = r0 + quad * 4 + r;
            if (row < NN) *(unsigned*)&xsc[(size_t)row * 4] = ebu[r];
        }
    }
}

// ---------------- output GEMM: out[perm[i]] = h[i] @ Wout + bout ----------------
__global__ __launch_bounds__(256) void k_gemm_out(const __bf16* __restrict__ A, const int* __restrict__ perm,
                                                  const __bf16* __restrict__ Bhi, const __bf16* __restrict__ Blo,
                                                  const float* __restrict__ bout, float* __restrict__ out) {
    __shared__ __bf16 Bs[2 * 48 * DH];
    int tid = threadIdx.x;
    {
        const f32x4* sh = (const f32x4*)Bhi;
        const f32x4* sl = (const f32x4*)Blo;
        f32x4* dh = (f32x4*)Bs;
        f32x4* dl = (f32x4*)(Bs + 48 * DH);
#pragma unroll
        for (int i = 0; i < 3; ++i) {
            dh[tid + i * 256] = sh[tid + i * 256];
            dl[tid + i * 256] = sl[tid + i * 256];
        }
    }
    __syncthreads();

    int wave = tid >> 6, lane = tid & 63;
    int n = lane & 15, quad = lane >> 4;
    int r0 = blockIdx.x * 64 + wave * 16;
    int arow = r0 + n;
    if (arow > NN - 1) arow = NN - 1;
    const __bf16* pa = A + (size_t)arow * DH + quad * 8;

    f32x4 acc[3];
#pragma unroll
    for (int t = 0; t < 3; ++t) acc[t] = (f32x4){0.f, 0.f, 0.f, 0.f};

#pragma unroll
    for (int ks = 0; ks < 4; ++ks) {
        bf16x8 av = *(const bf16x8*)(pa + ks * 32);
#pragma unroll
        for (int t = 0; t < 3; ++t) {
            int base = ((t * 4 + ks) * 64 + lane) * 8;
            bf16x8 bh = *(const bf16x8*)&Bs[base];
            bf16x8 bl = *(const bf16x8*)&Bs[48 * DH + base];
            acc[t] = MFMA(av, bh, acc[t]);
            acc[t] = MFMA(av, bl, acc[t]);
        }
    }

    int prow[4];
#pragma unroll
    for (int r = 0; r < 4; ++r) {
        int row = r0 + quad * 4 + r;
        prow[r] = (row < NN) ? perm[row] : 0;
    }

#pragma unroll
    for (int t = 0; t < 3; ++t) {
        int j = t * 16 + n;
        float bj = (j < 40) ? bout[j] : 0.f;
#pragma unroll
        for (int r = 0; r < 4; ++r) {
            int row = r0 + quad * 4 + r;
            if (row < NN && j < 40) out[(size_t)prow[r] * 40 + j] = acc[t][r] + bj;
        }
    }
}

// ---------------- fused slot-reduce + BN-finalize + update + int8 re-encode ----------------
// reads a8+asc (int8 GEMM output), hin (bf16); writes h (bf16) + h8/hsc (int8)
__global__ __launch_bounds__(256) void k_update(const unsigned char* __restrict__ a8,
                                                const unsigned char* __restrict__ asc,
                                                const __bf16* __restrict__ hin,
                                                __bf16* __restrict__ hout,
                                                unsigned char* __restrict__ h8, unsigned char* __restrict__ hsc,
                                                const float* __restrict__ stats32,
                                                const float* __restrict__ gamma, const float* __restrict__ bbeta) {
    __shared__ float scb[DH], shb[DH];
    int tid = threadIdx.x;
    if (tid < DH) {
        float s = 0.f, q = 0.f;
#pragma unroll
        for (int sl = 0; sl < NSLOT; ++sl) {
            s += stats32[(size_t)sl * 256 + tid];
            q += stats32[(size_t)sl * 256 + 128 + tid];
        }
        float mu = s * (1.0f / NN);
        float var = q * (1.0f / NN) - mu * mu;
        if (var < 0.f) var = 0.f;
        float sc = gamma[tid] * rsqrtf(var + 1e-5f);
        scb[tid] = sc;
        shb[tid] = bbeta[tid] - mu * sc;
    }
    __syncthreads();

    int idx = blockIdx.x * 256 + tid;
    int sub = idx & 15;
    int row = idx >> 4;
    int j0 = sub * 8;
    unsigned wpos = ((sub >> 3) & 1) * 64 + (sub & 3) * 16 + ((sub >> 2) & 1) * 8;
    uint2 ua = *(const uint2*)&a8[(size_t)row * 128 + wpos];
    float sA = dec_scale(*(const unsigned*)&asc[(size_t)row * 4], sub >> 2);
    bf16x8 hv = ((const bf16x8*)hin)[idx];
    bf16x8 o;
    float vv[8];
    float mx = 0.f;
#pragma unroll
    for (int c = 0; c < 8; ++c) {
        unsigned byte = ((c < 4 ? (ua.x >> (8 * c)) : (ua.y >> (8 * (c - 4)))) & 0xffu);
        float ad = ((float)byte - 128.f) * sA;
        int j = j0 + c;
        float v = fmaxf(fmaf(ad, scb[j], shb[j]) + (float)hv[c], 0.f);
        vv[c] = v;
        mx = fmaxf(mx, v);          // relu'd: v >= 0
        o[c] = (__bf16)v;
    }
    ((bf16x8*)hout)[idx] = o;

    // group max across the 4 threads sharing cols [ks*32, ks*32+32)
    mx = fmaxf(mx, __shfl_xor(mx, 1));
    mx = fmaxf(mx, __shfl_xor(mx, 2));
    unsigned int em = (__float_as_uint(mx) >> 23) & 0xffu;
    unsigned int eb;
    float sinv;
    if (em < 7) { eb = 0; sinv = 0.f; }
    else { eb = em - 6; sinv = __uint_as_float((254 - eb) << 23); }
    if ((tid & 3) == 0) hsc[(size_t)row * 4 + (sub >> 2)] = (unsigned char)eb;
    uint2 pk;
    pk.x = 0; pk.y = 0;
#pragma unroll
    for (int c = 0; c < 4; ++c) {
        unsigned int q0 = (unsigned int)rintf(fminf(fmaf(vv[c], sinv, 128.f), 255.f));
        unsigned int q1 = (unsigned int)rintf(fminf(fmaf(vv[4 + c], sinv, 128.f), 255.f));
        pk.x |= q0 << (8 * c);
        pk.y |= q1 << (8 * c);
    }
    *(uint2*)&h8[(size_t)row * 128 + wpos] = pk;
}

extern "C" void kernel_launch(void* const* d_in, const int* in_sizes, int n_in,
                              void* d_out, int out_size, void* d_ws, size_t ws_size,
                              hipStream_t stream) {
    const float* x = (const float*)d_in[0];
    const float* ew = (const float*)d_in[1];
    const float* Win = (const float*)d_in[2];
    const float* bin = (const float*)d_in[3];
    const float* convW = (const float*)d_in[4];
    const float* gamma = (const float*)d_in[5];
    const float* bbeta = (const float*)d_in[6];
    const float* Wout = (const float*)d_in[7];
    const float* bout = (const float*)d_in[8];
    const int* erow = (const int*)d_in[9];
    const int* ecol = (const int*)d_in[10];
    float* out = (float*)d_out;

    char* wsp = (char*)d_ws;
    size_t off = 0;
    auto alloc = [&](size_t bytes) -> void* {
        void* p = wsp + off;
        off += (bytes + 255) & ~(size_t)255;
        return p;
    };
    __bf16* x0 = (__bf16*)alloc((size_t)NN * DH * 2);
    __bf16* h = (__bf16*)alloc((size_t)NN * DH * 2);
    unsigned char* a8 = (unsigned char*)alloc((size_t)NN * DH);
    unsigned char* asc = (unsigned char*)alloc((size_t)NN * 4);
    unsigned char* x08 = (unsigned char*)alloc((size_t)NN * DH);
    unsigned char* h8 = (unsigned char*)alloc((size_t)NN * DH);
    unsigned char* x0sc = (unsigned char*)alloc((size_t)NN * 4);
    unsigned char* hsc = (unsigned char*)alloc((size_t)NN * 4);
    int* rp = (int*)alloc((NN + 1) * 4);
    int* perm = (int*)alloc((size_t)NN * 4);
    int* iperm = (int*)alloc((size_t)NN * 4);
    int* cnt2 = (int*)alloc((size_t)NN * 4);
    int* dpre = (int*)alloc(64 * 4);
    // zero-init region: cnt | fil | stats32 | dbin | dfil as ONE memset
    size_t zero_bytes = (size_t)NN * 4 + (size_t)NN * 4 + (size_t)NL * NSLOT * 256 * 4 + 128 * 4;
    int* cnt = (int*)alloc(zero_bytes);
    int* fil = cnt + NN;
    float* stats32 = (float*)(fil + NN);
    int* dbin = (int*)(stats32 + (size_t)NL * NSLOT * 256);
    int* dfil = dbin + 64;
    int2* ep = (int2*)alloc((size_t)EE * 8);
    int* part = (int*)alloc(256 * 4);
    __bf16* Bhi = (__bf16*)alloc((size_t)(NL + 1) * DH * DH * 2);
    __bf16* Blo = (__bf16*)alloc((size_t)(NL + 1) * DH * DH * 2);
    __bf16* Bohi = (__bf16*)alloc((size_t)DH * 48 * 2);
    __bf16* Bolo = (__bf16*)alloc((size_t)DH * 48 * 2);

    hipMemsetAsync(cnt, 0, zero_bytes, stream);

    k_hist<<<3125, 256, 0, stream>>>(erow, cnt);
    k_dhist<<<391, 256, 0, stream>>>(cnt, dbin);
    k_pscan<<<1, 64, 0, stream>>>(dbin, dpre);
    k_pscatter<<<391, 256, 0, stream>>>(cnt, dpre, dfil, perm);
    k_iperm<<<391, 256, 0, stream>>>(perm, cnt, iperm, cnt2);
    k_scan1<<<196, 512, 0, stream>>>(cnt2, rp, part);
    k_scan2<<<1, 256, 0, stream>>>(part, 196);
    k_scan3<<<196, 512, 0, stream>>>(rp, part);
    k_fill<<<3125, 256, 0, stream>>>(erow, ecol, ew, rp, iperm, fil, ep);

    k_prep_w<<<NL + 1, 256, 0, stream>>>(convW, Win, Bhi, Blo);
    k_prep_out<<<1, 256, 0, stream>>>(Wout, Bohi, Bolo);

    k_lin_in<<<SG_GRID, 512, 0, stream>>>(x, perm, Bhi + (size_t)NL * DH * DH, Blo + (size_t)NL * DH * DH,
                                          bin, x0, x08, x0sc);

    for (int l = 0; l < NL; ++l) {
        const unsigned char* hin8 = (l == 0) ? x08 : h8;
        const unsigned char* hinsc = (l == 0) ? x0sc : hsc;
        const __bf16* hin = (l == 0) ? x0 : h;
        float* st = stats32 + (size_t)l * NSLOT * 256;
        k_spmm_gemm<<<SG_GRID, 512, 0, stream>>>(hin8, hinsc, x08, x0sc, rp, ep, a8, asc,
                                                 Bhi + (size_t)l * DH * DH, Blo + (size_t)l * DH * DH, st);
        k_update<<<6250, 256, 0, stream>>>(a8, asc, hin, h, h8, hsc, st, gamma + l * DH, bbeta + l * DH);
    }
    k_gemm_out<<<GEMM_GRID, 256, 0, stream>>>(h, perm, Bohi, Bolo, bout, out);
}

// Round 11
// 1161.740 us; speedup vs baseline: 1.0268x; 1.0268x over previous
//
#include <hip/hip_runtime.h>
#include <math.h>

#define NN 100000
#define EE 800000
#define DH 128
#define NL 16
#define GEMM_GRID 1563
#define SG_GRID 782      // ceil(100000 / 128) for 8-wave (512-thread) blocks
#define SGQ_GRID 391     // ceil(100000 / 256) for 16-wave (1024-thread) spmm blocks
#define NSLOT 32

typedef __bf16 bf16x8 __attribute__((ext_vector_type(8)));
typedef float f32x4 __attribute__((ext_vector_type(4)));

// ---------------- CSR build ----------------
__global__ void k_hist(const int* __restrict__ row, int* __restrict__ cnt) {
    int e = blockIdx.x * 256 + threadIdx.x;
    if (e < EE) atomicAdd(&cnt[__builtin_nontemporal_load(&row[e])], 1);
}

__global__ void k_scan1(const int* __restrict__ cnt, int* __restrict__ rp, int* __restrict__ part) {
    __shared__ int buf[512];
    int tid = threadIdx.x;
    int i = blockIdx.x * 512 + tid;
    int v = (i < NN) ? cnt[i] : 0;
    buf[tid] = v;
    __syncthreads();
    for (int off = 1; off < 512; off <<= 1) {
        int x = (tid >= off) ? buf[tid - off] : 0;
        __syncthreads();
        buf[tid] += x;
        __syncthreads();
    }
    if (i < NN) rp[i] = buf[tid] - v;
    if (tid == 511) part[blockIdx.x] = buf[511];
}

__global__ void k_scan2(int* __restrict__ part, int nparts) {
    __shared__ int buf[256];
    int tid = threadIdx.x;
    int v = (tid < nparts) ? part[tid] : 0;
    buf[tid] = v;
    __syncthreads();
    for (int off = 1; off < 256; off <<= 1) {
        int x = (tid >= off) ? buf[tid - off] : 0;
        __syncthreads();
        buf[tid] += x;
        __syncthreads();
    }
    if (tid < nparts) part[tid] = buf[tid] - v;
}

__global__ void k_scan3(int* __restrict__ rp, const int* __restrict__ part) {
    int i = blockIdx.x * 512 + threadIdx.x;
    if (i < NN) rp[i] += part[blockIdx.x];
    if (i == 0) rp[NN] = EE;
}

// ---------------- degree-sort permutation (counting sort, 64 bins, DESCENDING for LPT) ----------------
__global__ void k_dhist(const int* __restrict__ cnt, int* __restrict__ dbin) {
    __shared__ int lb[64];
    int tid = threadIdx.x;
    if (tid < 64) lb[tid] = 0;
    __syncthreads();
    int i = blockIdx.x * 256 + tid;
    if (i < NN) {
        int d = cnt[i];
        if (d > 63) d = 63;
        atomicAdd(&lb[63 - d], 1);
    }
    __syncthreads();
    if (tid < 64 && lb[tid]) atomicAdd(&dbin[tid], lb[tid]);
}

__global__ void k_pscan(const int* __restrict__ dbin, int* __restrict__ dpre) {
    if (threadIdx.x == 0) {
        int s = 0;
        for (int i = 0; i < 64; ++i) { dpre[i] = s; s += dbin[i]; }
    }
}

__global__ void k_pscatter(const int* __restrict__ cnt, const int* __restrict__ dpre,
                           int* __restrict__ dfil, int* __restrict__ perm) {
    __shared__ int lcnt[64], lbase[64];
    int tid = threadIdx.x;
    if (tid < 64) lcnt[tid] = 0;
    __syncthreads();
    int i = blockIdx.x * 256 + tid;
    int b = 0, loc = 0;
    bool ok = (i < NN);
    if (ok) {
        int d = cnt[i];
        if (d > 63) d = 63;
        b = 63 - d;
        loc = atomicAdd(&lcnt[b], 1);
    }
    __syncthreads();
    if (tid < 64 && lcnt[tid]) lbase[tid] = atomicAdd(&dfil[tid], lcnt[tid]);
    __syncthreads();
    if (ok) perm[dpre[b] + lbase[b] + loc] = i;
}

// iperm[perm[i]] = i; cnt2[i] = degree of i-th sorted node (for permuted-space rp)
__global__ void k_iperm(const int* __restrict__ perm, const int* __restrict__ cnt,
                        int* __restrict__ iperm, int* __restrict__ cnt2) {
    int i = blockIdx.x * 256 + threadIdx.x;
    if (i < NN) {
        int p = perm[i];
        iperm[p] = i;
        cnt2[i] = cnt[p];
    }
}

// ---------------- k_fill: single pass, nt loads (read-side fix verified in R10) ----------------
// WRITE amplification (~55MB for 6.4MB ep) is intrinsic to random 8B scatters;
// nt stores were null on the write side (R10 counter evidence). Parked.
__global__ void k_fill(const int* __restrict__ row, const int* __restrict__ col,
                       const float* __restrict__ w, const int* __restrict__ rp,
                       const int* __restrict__ iperm,
                       int* __restrict__ fil, int2* __restrict__ ep) {
    int e = blockIdx.x * 256 + threadIdx.x;
    if (e >= EE) return;
    int r = iperm[__builtin_nontemporal_load(&row[e])];
    int c = iperm[__builtin_nontemporal_load(&col[e])];
    float wv = 0.9f * __builtin_nontemporal_load(&w[e]);
    int pos = rp[r] + atomicAdd(&fil[r], 1);
    unsigned long long v = (unsigned long long)(unsigned)c |
                           ((unsigned long long)(unsigned)__float_as_int(wv) << 32);
    __builtin_nontemporal_store(v, (unsigned long long*)&ep[pos]);
}

// ---------------- weight prep: split hi/lo bf16 + swizzle to MFMA fragment order ----------------
__global__ void k_prep_w(const float* __restrict__ convW, const float* __restrict__ Win,
                         __bf16* __restrict__ Bhi, __bf16* __restrict__ Blo) {
    int l = blockIdx.x;
    const float* W;
    float beta, ob;
    if (l < NL) {
        beta = logf(0.5f / (float)(l + 1) + 1.0f);
        ob = 1.0f - beta;
        W = convW + (size_t)l * DH * DH;
    } else {
        beta = 1.0f;
        ob = 0.0f;
        W = Win;
    }
    __bf16* bh = Bhi + (size_t)l * DH * DH;
    __bf16* bl = Blo + (size_t)l * DH * DH;
    for (int i = threadIdx.x; i < DH * DH; i += 256) {
        int k = i >> 7, j = i & 127;
        float v = beta * W[i] + ((k == j) ? ob : 0.f);
        __bf16 hv = (__bf16)v;
        int t = j >> 4, n = j & 15, ks = k >> 5, quad = (k >> 3) & 3, e = k & 7;
        int off = ((t * 4 + ks) * 64 + quad * 16 + n) * 8 + e;
        bh[off] = hv;
        bl[off] = (__bf16)(v - (float)hv);
    }
}

__global__ void k_prep_out(const float* __restrict__ Wout, __bf16* __restrict__ Bhi, __bf16* __restrict__ Blo) {
    for (int i = threadIdx.x; i < DH * 48; i += 256) {
        int k = i / 48, j = i % 48;
        float v = (j < 40) ? Wout[k * 40 + j] : 0.f;
        __bf16 hv = (__bf16)v;
        int t = j >> 4, n = j & 15, ks = k >> 5, quad = (k >> 3) & 3, e = k & 7;
        int off = ((t * 4 + ks) * 64 + quad * 16 + n) * 8 + e;
        Bhi[off] = hv;
        Blo[off] = (__bf16)(v - (float)hv);
    }
}

__device__ inline void split8(const float* p, bf16x8& hi, bf16x8& lo) {
    f32x4 v0 = *(const f32x4*)p;
    f32x4 v1 = *(const f32x4*)(p + 4);
#pragma unroll
    for (int j = 0; j < 4; ++j) {
        __bf16 h0 = (__bf16)v0[j];
        hi[j] = h0;
        lo[j] = (__bf16)(v0[j] - (float)h0);
        __bf16 h1 = (__bf16)v1[j];
        hi[4 + j] = h1;
        lo[4 + j] = (__bf16)(v1[j] - (float)h1);
    }
}

#define MFMA(a, b, c) __builtin_amdgcn_mfma_f32_16x16x32_bf16(a, b, c, 0, 0, 0)

// ---------------- int8 group quantization helpers ----------------
__device__ inline float dec_scale(unsigned int sc4, int ks) {
    return __uint_as_float(((sc4 >> (8 * ks)) & 0xffu) << 23);
}

#define DEC_DW(dw, wsv, a0, a1, a2, a3)                         \
    {                                                           \
        a0 = fmaf(wsv, (float)((dw)&0xffu), a0);                \
        a1 = fmaf(wsv, (float)(((dw) >> 8) & 0xffu), a1);       \
        a2 = fmaf(wsv, (float)(((dw) >> 16) & 0xffu), a2);      \
        a3 = fmaf(wsv, (float)((dw) >> 24), a3);                \
    }

#define EDGE_FMA(S4, W, RA, RB)                                       \
    {                                                                 \
        float _w = (W);                                               \
        float _w0 = _w * dec_scale(S4, 0);                            \
        float _w1 = _w * dec_scale(S4, 1);                            \
        float _w2 = _w * dec_scale(S4, 2);                            \
        float _w3 = _w * dec_scale(S4, 3);                            \
        sw0 += _w0; sw1 += _w1; sw2 += _w2; sw3 += _w3;               \
        DEC_DW((RA).x, _w0, acc[0][0], acc[0][1], acc[0][2], acc[0][3]); \
        DEC_DW((RA).y, _w0, acc[0][4], acc[0][5], acc[0][6], acc[0][7]); \
        DEC_DW((RA).z, _w1, acc[1][0], acc[1][1], acc[1][2], acc[1][3]); \
        DEC_DW((RA).w, _w1, acc[1][4], acc[1][5], acc[1][6], acc[1][7]); \
        DEC_DW((RB).x, _w2, acc[2][0], acc[2][1], acc[2][2], acc[2][3]); \
        DEC_DW((RB).y, _w2, acc[2][4], acc[2][5], acc[2][6], acc[2][7]); \
        DEC_DW((RB).z, _w3, acc[3][0], acc[3][1], acc[3][2], acc[3][3]); \
        DEC_DW((RB).w, _w3, acc[3][4], acc[3][5], acc[3][6], acc[3][7]); \
    }

// ---------------- FUSED SpMM + mix + layer GEMM (int8 gather, pipelined, 1024 threads) ----------------
// Reverted to bf16 aout (R10's int8-a epilogue byte-stores cost ~4us/layer).
// 16 waves share one 64KB B-tile; post-MFMA __syncthreads lets Bs be reused as
// the stats reduction scratch -> LDS = 64KB exactly -> 2 blocks/CU = 32 waves/CU.
// R4's occupancy-null ran under the old bf16-row pattern-ceiling regime; the
// int8+pipelined gather is latency-limited (VALUBusy 24-28% @ 16 waves), so
// occupancy is re-tested here. launch_bounds(1024,4): no forced spill (cap 128);
// if allocator lands <=64 (56 in R8/R9), HW gives 8 waves/SIMD automatically.
__global__ __launch_bounds__(1024, 4) void k_spmm_gemm(const unsigned char* __restrict__ hin8,
                                                       const unsigned char* __restrict__ hinsc,
                                                       const unsigned char* __restrict__ x08,
                                                       const unsigned char* __restrict__ x0sc,
                                                       const int* __restrict__ rp, const int2* __restrict__ ep,
                                                       __bf16* __restrict__ aout,
                                                       const __bf16* __restrict__ Bhi, const __bf16* __restrict__ Blo,
                                                       float* __restrict__ stats32) {
    __shared__ __bf16 Bs[2 * DH * DH];  // [hi|lo] in MFMA fragment order; reused as red after MFMA
    int tid = threadIdx.x;
    {
        const f32x4* sh = (const f32x4*)Bhi;
        const f32x4* sl = (const f32x4*)Blo;
        f32x4* dh = (f32x4*)Bs;
        f32x4* dl = (f32x4*)(Bs + DH * DH);
#pragma unroll
        for (int i = 0; i < 2; ++i) {
            dh[tid + i * 1024] = sh[tid + i * 1024];
            dl[tid + i * 1024] = sl[tid + i * 1024];
        }
    }
    // no sync yet: gather phase doesn't touch Bs; sync sits right before MFMA.

    int wave = tid >> 6, lane = tid & 63;
    int n = lane & 15, quad = lane >> 4;
    int r0 = blockIdx.x * 256 + wave * 16;
    int node = r0 + n;
    int nc = (node < NN) ? node : (NN - 1);

    float acc[4][8];
#pragma unroll
    for (int ks = 0; ks < 4; ++ks)
#pragma unroll
        for (int c = 0; c < 8; ++c) acc[ks][c] = 0.f;
    float sw0 = 0.f, sw1 = 0.f, sw2 = 0.f, sw3 = 0.f;

    // x0 self-term loads
    unsigned xs4 = *(const unsigned*)&x0sc[(size_t)nc * 4];
    const unsigned char* xb = x08 + (size_t)nc * 128 + quad * 16;
    uint4 xa = *(const uint4*)xb;
    uint4 xc = *(const uint4*)(xb + 64);

    int s = 0, e = 0;
    if (node < NN) { s = rp[node]; e = rp[node + 1]; }
    int cnt = e - s;
    int npairs = cnt >> 1;

    const unsigned char* hb = hin8 + quad * 16;

    int2 cP0, cP1, fP0, fP1;
    unsigned cS0, cS1;
    uint4 cA0, cB0, cA1, cB1;
    if (npairs > 0) {
        cP0 = ep[s]; cP1 = ep[s + 1];
        cS0 = *(const unsigned*)&hinsc[(size_t)cP0.x * 4];
        cS1 = *(const unsigned*)&hinsc[(size_t)cP1.x * 4];
        const unsigned char* b0 = hb + (size_t)cP0.x * 128;
        const unsigned char* b1 = hb + (size_t)cP1.x * 128;
        cA0 = *(const uint4*)b0; cB0 = *(const uint4*)(b0 + 64);
        cA1 = *(const uint4*)b1; cB1 = *(const uint4*)(b1 + 64);
        int jf = s + 2; if (jf > EE - 2) jf = EE - 2;
        fP0 = ep[jf]; fP1 = ep[jf + 1];
    }

    EDGE_FMA(xs4, 0.1f, xa, xc);   // weight 0.1 on x0 (alpha mix)

    int j = s;
    for (int it = 0; it < npairs; ++it) {
        int j2 = j + 4; if (j2 > EE - 2) j2 = EE - 2;
        int2 eN0 = ep[j2], eN1 = ep[j2 + 1];
        unsigned tS0 = *(const unsigned*)&hinsc[(size_t)fP0.x * 4];
        unsigned tS1 = *(const unsigned*)&hinsc[(size_t)fP1.x * 4];
        const unsigned char* b0 = hb + (size_t)fP0.x * 128;
        const unsigned char* b1 = hb + (size_t)fP1.x * 128;
        uint4 tA0 = *(const uint4*)b0, tB0 = *(const uint4*)(b0 + 64);
        uint4 tA1 = *(const uint4*)b1, tB1 = *(const uint4*)(b1 + 64);
        EDGE_FMA(cS0, __int_as_float(cP0.y), cA0, cB0);
        EDGE_FMA(cS1, __int_as_float(cP1.y), cA1, cB1);
        cP0 = fP0; cP1 = fP1; fP0 = eN0; fP1 = eN1;
        cS0 = tS0; cS1 = tS1;
        cA0 = tA0; cB0 = tB0; cA1 = tA1; cB1 = tB1;
        j += 2;
    }
    if (cnt & 1) {
        int2 pe = ep[e - 1];
        unsigned s4 = *(const unsigned*)&hinsc[(size_t)pe.x * 4];
        const unsigned char* bp = hb + (size_t)pe.x * 128;
        uint4 ra = *(const uint4*)bp, rb = *(const uint4*)(bp + 64);
        EDGE_FMA(s4, __int_as_float(pe.y), ra, rb);
    }

    // bias correction (u8 -> u8-128) + bf16 A fragments
    bf16x8 av[4];
    {
        float sws[4] = {sw0, sw1, sw2, sw3};
#pragma unroll
        for (int ks = 0; ks < 4; ++ks)
#pragma unroll
            for (int c = 0; c < 8; ++c)
                av[ks][c] = (__bf16)(acc[ks][c] - 128.0f * sws[ks]);
    }

    __syncthreads();  // Bs staging complete across all waves

    f32x4 gacc[8];
#pragma unroll
    for (int t = 0; t < 8; ++t) gacc[t] = (f32x4){0.f, 0.f, 0.f, 0.f};

#pragma unroll
    for (int ks = 0; ks < 4; ++ks) {
#pragma unroll
        for (int t = 0; t < 8; ++t) {
            int base = ((t * 4 + ks) * 64 + lane) * 8;
            bf16x8 bh = *(const bf16x8*)&Bs[base];
            bf16x8 bl = *(const bf16x8*)&Bs[DH * DH + base];
            gacc[t] = MFMA(av[ks], bh, gacc[t]);
            gacc[t] = MFMA(av[ks], bl, gacc[t]);
        }
    }

    __syncthreads();  // all waves done reading Bs -> reuse as reduction scratch
    float* red = (float*)Bs;   // [2][16][DH] = 16KB of the 64KB

#pragma unroll
    for (int t = 0; t < 8; ++t) {
        float sm = 0.f, qq = 0.f;
#pragma unroll
        for (int r = 0; r < 4; ++r) {
            int row = r0 + quad * 4 + r;
            float v = gacc[t][r];
            if (row < NN) {
                aout[(size_t)row * DH + t * 16 + n] = (__bf16)v;
                sm += v;
                qq += v * v;
            }
        }
        sm += __shfl_xor(sm, 16); sm += __shfl_xor(sm, 32);
        qq += __shfl_xor(qq, 16); qq += __shfl_xor(qq, 32);
        if (quad == 0) {
            red[(0 * 16 + wave) * DH + t * 16 + n] = sm;
            red[(1 * 16 + wave) * DH + t * 16 + n] = qq;
        }
    }
    __syncthreads();
    if (tid < 256) {
        int which = tid >> 7, jj = tid & 127;
        float tot = 0.f;
#pragma unroll
        for (int w = 0; w < 16; ++w) tot += red[(which * 16 + w) * DH + jj];
        atomicAdd(&stats32[(size_t)(blockIdx.x & (NSLOT - 1)) * 256 + tid], tot);
    }
}

// ---------------- input GEMM + fused int8 encode: x0/x08/xsc from X[perm[i]] ----------------
__global__ __launch_bounds__(512, 4) void k_lin_in(const float* __restrict__ X, const int* __restrict__ perm,
                                                   const __bf16* __restrict__ Bhi, const __bf16* __restrict__ Blo,
                                                   const float* __restrict__ bin, __bf16* __restrict__ x0,
                                                   unsigned char* __restrict__ x08, unsigned char* __restrict__ xsc) {
    __shared__ __bf16 Bs[2 * DH * DH];
    int tid = threadIdx.x;
    {
        const f32x4* sh = (const f32x4*)Bhi;
        const f32x4* sl = (const f32x4*)Blo;
        f32x4* dh = (f32x4*)Bs;
        f32x4* dl = (f32x4*)(Bs + DH * DH);
#pragma unroll
        for (int i = 0; i < 4; ++i) {
            dh[tid + i * 512] = sh[tid + i * 512];
            dl[tid + i * 512] = sl[tid + i * 512];
        }
    }
    __syncthreads();

    int wave = tid >> 6, lane = tid & 63;
    int n = lane & 15, quad = lane >> 4;
    int r0 = blockIdx.x * 128 + wave * 16;
    int arow = r0 + n;
    if (arow > NN - 1) arow = NN - 1;
    const float* pa = X + (size_t)perm[arow] * DH + quad * 8;

    f32x4 acc[8];
#pragma unroll
    for (int t = 0; t < 8; ++t) acc[t] = (f32x4){0.f, 0.f, 0.f, 0.f};

#pragma unroll
    for (int ks = 0; ks < 4; ++ks) {
        bf16x8 ah, al;
        split8(pa + ks * 32, ah, al);
#pragma unroll
        for (int t = 0; t < 8; ++t) {
            int base = ((t * 4 + ks) * 64 + lane) * 8;
            bf16x8 bh = *(const bf16x8*)&Bs[base];
            bf16x8 bl = *(const bf16x8*)&Bs[DH * DH + base];
            acc[t] = MFMA(ah, bh, acc[t]);
            acc[t] = MFMA(al, bh, acc[t]);
            acc[t] = MFMA(ah, bl, acc[t]);
        }
    }

#pragma unroll
    for (int t = 0; t < 8; ++t) {
        float bj = bin[t * 16 + n];
#pragma unroll
        for (int r = 0; r < 4; ++r) {
            float v = fmaxf(acc[t][r] + bj, 0.f);
            acc[t][r] = v;
            int row = r0 + quad * 4 + r;
            if (row < NN) x0[(size_t)row * DH + t * 16 + n] = (__bf16)v;
        }
    }

    // fused int8 encode (bf16 rounding first to match the old cvt8 source data)
    float m[4][4];
#pragma unroll
    for (int r = 0; r < 4; ++r)
#pragma unroll
        for (int g = 0; g < 4; ++g) {
            float v0 = (float)(__bf16)acc[2 * g][r];
            float v1 = (float)(__bf16)acc[2 * g + 1][r];
            m[r][g] = fmaxf(fabsf(v0), fabsf(v1));
        }
#pragma unroll
    for (int d = 1; d <= 8; d <<= 1)
#pragma unroll
        for (int r = 0; r < 4; ++r)
#pragma unroll
            for (int g = 0; g < 4; ++g)
                m[r][g] = fmaxf(m[r][g], __shfl_xor(m[r][g], d));
    unsigned ebu[4];
    float sinv[4][4];
#pragma unroll
    for (int r = 0; r < 4; ++r) {
        unsigned u32 = 0;
#pragma unroll
        for (int g = 0; g < 4; ++g) {
            unsigned em = (__float_as_uint(m[r][g]) >> 23) & 0xffu;
            unsigned eb;
            float si;
            if (em < 7) { eb = 0; si = 0.f; }
            else { eb = em - 6; si = __uint_as_float((254 - eb) << 23); }
            u32 |= eb << (8 * g);
            sinv[r][g] = si;
        }
        ebu[r] = u32;
    }
#pragma unroll
    for (int t = 0; t < 8; ++t) {
        int wb = (t >> 2) * 64 + ((((t & 1) << 1) | (n >> 3))) * 16 + ((t >> 1) & 1) * 8 + (n & 7);
#pragma unroll
        for (int r = 0; r < 4; ++r) {
            int row = r0 + quad * 4 + r;
            if (row < NN) {
                float v = (float)(__bf16)acc[t][r];
                unsigned qv = (unsigned)rintf(fminf(fmaf(v, sinv[r][t >> 1], 128.f), 255.f));
                x08[(size_t)row * 128 + wb] = (unsigned char)qv;
            }
        }
    }
    if (n == 0) {
#pragma unroll
        for (int r = 0; r < 4; ++r) {
            int row = r0 + quad * 4 + r;
            if (row < NN) *(unsigned*)&xsc[(size_t)row * 4] = ebu[r];
        }
    }
}

// ---------------- output GEMM: out[perm[i]] = h[i] @ Wout + bout ----------------
__global__ __launch_bounds__(256) void k_gemm_out(const __bf16* __restrict__ A, const int* __restrict__ perm,
                                                  const __bf16* __restrict__ Bhi, const __bf16* __restrict__ Blo,
                                                  const float* __restrict__ bout, float* __restrict__ out) {
    __shared__ __bf16 Bs[2 * 48 * DH];
    int tid = threadIdx.x;
    {
        const f32x4* sh = (const f32x4*)Bhi;
        const f32x4* sl = (const f32x4*)Blo;
        f32x4* dh = (f32x4*)Bs;
        f32x4* dl = (f32x4*)(Bs + 48 * DH);
#pragma unroll
        for (int i = 0; i < 3; ++i) {
            dh[tid + i * 256] = sh[tid + i * 256];
            dl[tid + i * 256] = sl[tid + i * 256];
        }
    }
    __syncthreads();

    int wave = tid >> 6, lane = tid & 63;
    int n = lane & 15, quad = lane >> 4;
    int r0 = blockIdx.x * 64 + wave * 16;
    int arow = r0 + n;
    if (arow > NN - 1) arow = NN - 1;
    const __bf16* pa = A + (size_t)arow * DH + quad * 8;

    f32x4 acc[3];
#pragma unroll
    for (int t = 0; t < 3; ++t) acc[t] = (f32x4){0.f, 0.f, 0.f, 0.f};

#pragma unroll
    for (int ks = 0; ks < 4; ++ks) {
        bf16x8 av = *(const bf16x8*)(pa + ks * 32);
#pragma unroll
        for (int t = 0; t < 3; ++t) {
            int base = ((t * 4 + ks) * 64 + lane) * 8;
            bf16x8 bh = *(const bf16x8*)&Bs[base];
            bf16x8 bl = *(const bf16x8*)&Bs[48 * DH + base];
            acc[t] = MFMA(av, bh, acc[t]);
            acc[t] = MFMA(av, bl, acc[t]);
        }
    }

    int prow[4];
#pragma unroll
    for (int r = 0; r < 4; ++r) {
        int row = r0 + quad * 4 + r;
        prow[r] = (row < NN) ? perm[row] : 0;
    }

#pragma unroll
    for (int t = 0; t < 3; ++t) {
        int j = t * 16 + n;
        float bj = (j < 40) ? bout[j] : 0.f;
#pragma unroll
        for (int r = 0; r < 4; ++r) {
            int row = r0 + quad * 4 + r;
            if (row < NN && j < 40) out[(size_t)prow[r] * 40 + j] = acc[t][r] + bj;
        }
    }
}

// ---------------- fused slot-reduce + BN-finalize + update + int8 re-encode (bf16 a input) ----------------
__global__ __launch_bounds__(256) void k_update(const __bf16* __restrict__ a, const __bf16* __restrict__ hin,
                                                __bf16* __restrict__ hout,
                                                unsigned char* __restrict__ h8, unsigned char* __restrict__ hsc,
                                                const float* __restrict__ stats32,
                                                const float* __restrict__ gamma, const float* __restrict__ bbeta) {
    __shared__ float scb[DH], shb[DH];
    int tid = threadIdx.x;
    if (tid < DH) {
        float s = 0.f, q = 0.f;
#pragma unroll
        for (int sl = 0; sl < NSLOT; ++sl) {
            s += stats32[(size_t)sl * 256 + tid];
            q += stats32[(size_t)sl * 256 + 128 + tid];
        }
        float mu = s * (1.0f / NN);
        float var = q * (1.0f / NN) - mu * mu;
        if (var < 0.f) var = 0.f;
        float sc = gamma[tid] * rsqrtf(var + 1e-5f);
        scb[tid] = sc;
        shb[tid] = bbeta[tid] - mu * sc;
    }
    __syncthreads();

    int idx = blockIdx.x * 256 + tid;
    int sub = idx & 15;
    int j0 = sub * 8;
    bf16x8 av = ((const bf16x8*)a)[idx];
    bf16x8 hv = ((const bf16x8*)hin)[idx];
    bf16x8 o;
    float vv[8];
    float mx = 0.f;
#pragma unroll
    for (int c = 0; c < 8; ++c) {
        int j = j0 + c;
        float v = fmaxf(fmaf((float)av[c], scb[j], shb[j]) + (float)hv[c], 0.f);
        vv[c] = v;
        mx = fmaxf(mx, v);          // relu'd: v >= 0
        o[c] = (__bf16)v;
    }
    ((bf16x8*)hout)[idx] = o;

    // group max across the 4 threads sharing cols [ks*32, ks*32+32)
    mx = fmaxf(mx, __shfl_xor(mx, 1));
    mx = fmaxf(mx, __shfl_xor(mx, 2));
    unsigned int em = (__float_as_uint(mx) >> 23) & 0xffu;
    unsigned int eb;
    float sinv;
    if (em < 7) { eb = 0; sinv = 0.f; }
    else { eb = em - 6; sinv = __uint_as_float((254 - eb) << 23); }
    if ((tid & 3) == 0) hsc[(size_t)(idx >> 4) * 4 + (sub >> 2)] = (unsigned char)eb;
    uint2 pk;
    pk.x = 0; pk.y = 0;
#pragma unroll
    for (int c = 0; c < 4; ++c) {
        unsigned int q0 = (unsigned int)rintf(fminf(fmaf(vv[c], sinv, 128.f), 255.f));
        unsigned int q1 = (unsigned int)rintf(fminf(fmaf(vv[4 + c], sinv, 128.f), 255.f));
        pk.x |= q0 << (8 * c);
        pk.y |= q1 << (8 * c);
    }
    // fragment-contiguous position: P = (ks>>1)*64 + q*16 + (ks&1)*8, ks=sub>>2, q=sub&3
    unsigned wpos = ((sub >> 3) & 1) * 64 + (sub & 3) * 16 + ((sub >> 2) & 1) * 8;
    *(uint2*)&h8[(size_t)(idx >> 4) * 128 + wpos] = pk;
}

extern "C" void kernel_launch(void* const* d_in, const int* in_sizes, int n_in,
                              void* d_out, int out_size, void* d_ws, size_t ws_size,
                              hipStream_t stream) {
    const float* x = (const float*)d_in[0];
    const float* ew = (const float*)d_in[1];
    const float* Win = (const float*)d_in[2];
    const float* bin = (const float*)d_in[3];
    const float* convW = (const float*)d_in[4];
    const float* gamma = (const float*)d_in[5];
    const float* bbeta = (const float*)d_in[6];
    const float* Wout = (const float*)d_in[7];
    const float* bout = (const float*)d_in[8];
    const int* erow = (const int*)d_in[9];
    const int* ecol = (const int*)d_in[10];
    float* out = (float*)d_out;

    char* wsp = (char*)d_ws;
    size_t off = 0;
    auto alloc = [&](size_t bytes) -> void* {
        void* p = wsp + off;
        off += (bytes + 255) & ~(size_t)255;
        return p;
    };
    __bf16* x0 = (__bf16*)alloc((size_t)NN * DH * 2);
    __bf16* h = (__bf16*)alloc((size_t)NN * DH * 2);
    __bf16* a = (__bf16*)alloc((size_t)NN * DH * 2);
    unsigned char* x08 = (unsigned char*)alloc((size_t)NN * DH);
    unsigned char* h8 = (unsigned char*)alloc((size_t)NN * DH);
    unsigned char* x0sc = (unsigned char*)alloc((size_t)NN * 4);
    unsigned char* hsc = (unsigned char*)alloc((size_t)NN * 4);
    int* rp = (int*)alloc((NN + 1) * 4);
    int* perm = (int*)alloc((size_t)NN * 4);
    int* iperm = (int*)alloc((size_t)NN * 4);
    int* cnt2 = (int*)alloc((size_t)NN * 4);
    int* dpre = (int*)alloc(64 * 4);
    // zero-init region: cnt | fil | stats32 | dbin | dfil as ONE memset
    size_t zero_bytes = (size_t)NN * 4 + (size_t)NN * 4 + (size_t)NL * NSLOT * 256 * 4 + 128 * 4;
    int* cnt = (int*)alloc(zero_bytes);
    int* fil = cnt + NN;
    float* stats32 = (float*)(fil + NN);
    int* dbin = (int*)(stats32 + (size_t)NL * NSLOT * 256);
    int* dfil = dbin + 64;
    int2* ep = (int2*)alloc((size_t)EE * 8);
    int* part = (int*)alloc(256 * 4);
    __bf16* Bhi = (__bf16*)alloc((size_t)(NL + 1) * DH * DH * 2);
    __bf16* Blo = (__bf16*)alloc((size_t)(NL + 1) * DH * DH * 2);
    __bf16* Bohi = (__bf16*)alloc((size_t)DH * 48 * 2);
    __bf16* Bolo = (__bf16*)alloc((size_t)DH * 48 * 2);

    hipMemsetAsync(cnt, 0, zero_bytes, stream);

    k_hist<<<3125, 256, 0, stream>>>(erow, cnt);
    k_dhist<<<391, 256, 0, stream>>>(cnt, dbin);
    k_pscan<<<1, 64, 0, stream>>>(dbin, dpre);
    k_pscatter<<<391, 256, 0, stream>>>(cnt, dpre, dfil, perm);
    k_iperm<<<391, 256, 0, stream>>>(perm, cnt, iperm, cnt2);
    k_scan1<<<196, 512, 0, stream>>>(cnt2, rp, part);
    k_scan2<<<1, 256, 0, stream>>>(part, 196);
    k_scan3<<<196, 512, 0, stream>>>(rp, part);
    k_fill<<<3125, 256, 0, stream>>>(erow, ecol, ew, rp, iperm, fil, ep);

    k_prep_w<<<NL + 1, 256, 0, stream>>>(convW, Win, Bhi, Blo);
    k_prep_out<<<1, 256, 0, stream>>>(Wout, Bohi, Bolo);

    k_lin_in<<<SG_GRID, 512, 0, stream>>>(x, perm, Bhi + (size_t)NL * DH * DH, Blo + (size_t)NL * DH * DH,
                                          bin, x0, x08, x0sc);

    for (int l = 0; l < NL; ++l) {
        const unsigned char* hin8 = (l == 0) ? x08 : h8;
        const unsigned char* hinsc = (l == 0) ? x0sc : hsc;
        const __bf16* hin = (l == 0) ? x0 : h;
        float* st = stats32 + (size_t)l * NSLOT * 256;
        k_spmm_gemm<<<SGQ_GRID, 1024, 0, stream>>>(hin8, hinsc, x08, x0sc, rp, ep, a,
                                                   Bhi + (size_t)l * DH * DH, Blo + (size_t)l * DH * DH, st);
        k_update<<<6250, 256, 0, stream>>>(a, hin, h, h8, hsc, st, gamma + l * DH, bbeta + l * DH);
    }
    k_gemm_out<<<GEMM_GRID, 256, 0, stream>>>(h, perm, Bohi, Bolo, bout, out);
}

// Round 13
// 1130.963 us; speedup vs baseline: 1.0548x; 1.0272x over previous
//
#include <hip/hip_runtime.h>
#include <math.h>

#define NN 100000
#define EE 800000
#define DH 128
#define NL 16
#define SG_GRID 782      // ceil(100000 / 128) for 8-wave (512-thread) blocks
#define NSLOT 32

typedef __bf16 bf16x8 __attribute__((ext_vector_type(8)));
typedef float f32x4 __attribute__((ext_vector_type(4)));

// ---------------- CSR build ----------------
__global__ void k_hist(const int* __restrict__ row, int* __restrict__ cnt) {
    int e = blockIdx.x * 256 + threadIdx.x;
    if (e < EE) atomicAdd(&cnt[__builtin_nontemporal_load(&row[e])], 1);
}

__global__ void k_scan1(const int* __restrict__ cnt, int* __restrict__ rp, int* __restrict__ part) {
    __shared__ int buf[512];
    int tid = threadIdx.x;
    int i = blockIdx.x * 512 + tid;
    int v = (i < NN) ? cnt[i] : 0;
    buf[tid] = v;
    __syncthreads();
    for (int off = 1; off < 512; off <<= 1) {
        int x = (tid >= off) ? buf[tid - off] : 0;
        __syncthreads();
        buf[tid] += x;
        __syncthreads();
    }
    if (i < NN) rp[i] = buf[tid] - v;
    if (tid == 511) part[blockIdx.x] = buf[511];
}

__global__ void k_scan2(int* __restrict__ part, int nparts) {
    __shared__ int buf[256];
    int tid = threadIdx.x;
    int v = (tid < nparts) ? part[tid] : 0;
    buf[tid] = v;
    __syncthreads();
    for (int off = 1; off < 256; off <<= 1) {
        int x = (tid >= off) ? buf[tid - off] : 0;
        __syncthreads();
        buf[tid] += x;
        __syncthreads();
    }
    if (tid < nparts) part[tid] = buf[tid] - v;
}

__global__ void k_scan3(int* __restrict__ rp, const int* __restrict__ part) {
    int i = blockIdx.x * 512 + threadIdx.x;
    if (i < NN) rp[i] += part[blockIdx.x];
    if (i == 0) rp[NN] = EE;
}

// ---------------- degree-sort permutation (counting sort, 64 bins, DESCENDING for LPT) ----------------
__global__ void k_dhist(const int* __restrict__ cnt, int* __restrict__ dbin) {
    __shared__ int lb[64];
    int tid = threadIdx.x;
    if (tid < 64) lb[tid] = 0;
    __syncthreads();
    int i = blockIdx.x * 256 + tid;
    if (i < NN) {
        int d = cnt[i];
        if (d > 63) d = 63;
        atomicAdd(&lb[63 - d], 1);
    }
    __syncthreads();
    if (tid < 64 && lb[tid]) atomicAdd(&dbin[tid], lb[tid]);
}

__global__ void k_pscan(const int* __restrict__ dbin, int* __restrict__ dpre) {
    if (threadIdx.x == 0) {
        int s = 0;
        for (int i = 0; i < 64; ++i) { dpre[i] = s; s += dbin[i]; }
    }
}

__global__ void k_pscatter(const int* __restrict__ cnt, const int* __restrict__ dpre,
                           int* __restrict__ dfil, int* __restrict__ perm) {
    __shared__ int lcnt[64], lbase[64];
    int tid = threadIdx.x;
    if (tid < 64) lcnt[tid] = 0;
    __syncthreads();
    int i = blockIdx.x * 256 + tid;
    int b = 0, loc = 0;
    bool ok = (i < NN);
    if (ok) {
        int d = cnt[i];
        if (d > 63) d = 63;
        b = 63 - d;
        loc = atomicAdd(&lcnt[b], 1);
    }
    __syncthreads();
    if (tid < 64 && lcnt[tid]) lbase[tid] = atomicAdd(&dfil[tid], lcnt[tid]);
    __syncthreads();
    if (ok) perm[dpre[b] + lbase[b] + loc] = i;
}

// iperm[perm[i]] = i; cnt2[i] = degree of i-th sorted node (for permuted-space rp)
__global__ void k_iperm(const int* __restrict__ perm, const int* __restrict__ cnt,
                        int* __restrict__ iperm, int* __restrict__ cnt2) {
    int i = blockIdx.x * 256 + threadIdx.x;
    if (i < NN) {
        int p = perm[i];
        iperm[p] = i;
        cnt2[i] = cnt[p];
    }
}

// ---------------- k_fill: single pass, nt loads (read-side fix, R10-verified) ----------------
__global__ void k_fill(const int* __restrict__ row, const int* __restrict__ col,
                       const float* __restrict__ w, const int* __restrict__ rp,
                       const int* __restrict__ iperm,
                       int* __restrict__ fil, int2* __restrict__ ep) {
    int e = blockIdx.x * 256 + threadIdx.x;
    if (e >= EE) return;
    int r = iperm[__builtin_nontemporal_load(&row[e])];
    int c = iperm[__builtin_nontemporal_load(&col[e])];
    float wv = 0.9f * __builtin_nontemporal_load(&w[e]);
    int pos = rp[r] + atomicAdd(&fil[r], 1);
    unsigned long long v = (unsigned long long)(unsigned)c |
                           ((unsigned long long)(unsigned)__float_as_int(wv) << 32);
    __builtin_nontemporal_store(v, (unsigned long long*)&ep[pos]);
}

// ---------------- weight prep: split hi/lo bf16 + swizzle to MFMA fragment order ----------------
__global__ void k_prep_w(const float* __restrict__ convW, const float* __restrict__ Win,
                         __bf16* __restrict__ Bhi, __bf16* __restrict__ Blo) {
    int l = blockIdx.x;
    const float* W;
    float beta, ob;
    if (l < NL) {
        beta = logf(0.5f / (float)(l + 1) + 1.0f);
        ob = 1.0f - beta;
        W = convW + (size_t)l * DH * DH;
    } else {
        beta = 1.0f;
        ob = 0.0f;
        W = Win;
    }
    __bf16* bh = Bhi + (size_t)l * DH * DH;
    __bf16* bl = Blo + (size_t)l * DH * DH;
    for (int i = threadIdx.x; i < DH * DH; i += 256) {
        int k = i >> 7, j = i & 127;
        float v = beta * W[i] + ((k == j) ? ob : 0.f);
        __bf16 hv = (__bf16)v;
        int t = j >> 4, n = j & 15, ks = k >> 5, quad = (k >> 3) & 3, e = k & 7;
        int off = ((t * 4 + ks) * 64 + quad * 16 + n) * 8 + e;
        bh[off] = hv;
        bl[off] = (__bf16)(v - (float)hv);
    }
}

__global__ void k_prep_out(const float* __restrict__ Wout, __bf16* __restrict__ Bhi, __bf16* __restrict__ Blo) {
    for (int i = threadIdx.x; i < DH * 48; i += 256) {
        int k = i / 48, j = i % 48;
        float v = (j < 40) ? Wout[k * 40 + j] : 0.f;
        __bf16 hv = (__bf16)v;
        int t = j >> 4, n = j & 15, ks = k >> 5, quad = (k >> 3) & 3, e = k & 7;
        int off = ((t * 4 + ks) * 64 + quad * 16 + n) * 8 + e;
        Bhi[off] = hv;
        Blo[off] = (__bf16)(v - (float)hv);
    }
}

__device__ inline void split8(const float* p, bf16x8& hi, bf16x8& lo) {
    f32x4 v0 = *(const f32x4*)p;
    f32x4 v1 = *(const f32x4*)(p + 4);
#pragma unroll
    for (int j = 0; j < 4; ++j) {
        __bf16 h0 = (__bf16)v0[j];
        hi[j] = h0;
        lo[j] = (__bf16)(v0[j] - (float)h0);
        __bf16 h1 = (__bf16)v1[j];
        hi[4 + j] = h1;
        lo[4 + j] = (__bf16)(v1[j] - (float)h1);
    }
}

#define MFMA(a, b, c) __builtin_amdgcn_mfma_f32_16x16x32_bf16(a, b, c, 0, 0, 0)

// ---------------- int8 group quantization helpers ----------------
__device__ inline float dec_scale(unsigned int sc4, int ks) {
    return __uint_as_float(((sc4 >> (8 * ks)) & 0xffu) << 23);
}

#define DEC_DW(dw, wsv, a0, a1, a2, a3)                         \
    {                                                           \
        a0 = fmaf(wsv, (float)((dw)&0xffu), a0);                \
        a1 = fmaf(wsv, (float)(((dw) >> 8) & 0xffu), a1);       \
        a2 = fmaf(wsv, (float)(((dw) >> 16) & 0xffu), a2);      \
        a3 = fmaf(wsv, (float)((dw) >> 24), a3);                \
    }

#define EDGE_FMA(S4, W, RA, RB)                                       \
    {                                                                 \
        float _w = (W);                                               \
        float _w0 = _w * dec_scale(S4, 0);                            \
        float _w1 = _w * dec_scale(S4, 1);                            \
        float _w2 = _w * dec_scale(S4, 2);                            \
        float _w3 = _w * dec_scale(S4, 3);                            \
        sw0 += _w0; sw1 += _w1; sw2 += _w2; sw3 += _w3;               \
        DEC_DW((RA).x, _w0, acc[0][0], acc[0][1], acc[0][2], acc[0][3]); \
        DEC_DW((RA).y, _w0, acc[0][4], acc[0][5], acc[0][6], acc[0][7]); \
        DEC_DW((RA).z, _w1, acc[1][0], acc[1][1], acc[1][2], acc[1][3]); \
        DEC_DW((RA).w, _w1, acc[1][4], acc[1][5], acc[1][6], acc[1][7]); \
        DEC_DW((RB).x, _w2, acc[2][0], acc[2][1], acc[2][2], acc[2][3]); \
        DEC_DW((RB).y, _w2, acc[2][4], acc[2][5], acc[2][6], acc[2][7]); \
        DEC_DW((RB).z, _w3, acc[3][0], acc[3][1], acc[3][2], acc[3][3]); \
        DEC_DW((RB).w, _w3, acc[3][4], acc[3][5], acc[3][6], acc[3][7]); \
    }

// ---------------- FUSED SpMM + mix + layer GEMM (int8 gather, pipelined, 512 threads) ----------------
__global__ __launch_bounds__(512, 4) void k_spmm_gemm(const unsigned char* __restrict__ hin8,
                                                      const unsigned char* __restrict__ hinsc,
                                                      const unsigned char* __restrict__ x08,
                                                      const unsigned char* __restrict__ x0sc,
                                                      const int* __restrict__ rp, const int2* __restrict__ ep,
                                                      __bf16* __restrict__ aout,
                                                      const __bf16* __restrict__ Bhi, const __bf16* __restrict__ Blo,
                                                      float* __restrict__ stats32) {
    __shared__ __bf16 Bs[2 * DH * DH];  // [hi|lo] in MFMA fragment order
    __shared__ float red[2][8][DH];
    int tid = threadIdx.x;
    {
        const f32x4* sh = (const f32x4*)Bhi;
        const f32x4* sl = (const f32x4*)Blo;
        f32x4* dh = (f32x4*)Bs;
        f32x4* dl = (f32x4*)(Bs + DH * DH);
#pragma unroll
        for (int i = 0; i < 4; ++i) {
            dh[tid + i * 512] = sh[tid + i * 512];
            dl[tid + i * 512] = sl[tid + i * 512];
        }
    }
    // no sync yet: gather phase doesn't touch Bs; sync sits right before MFMA.

    int wave = tid >> 6, lane = tid & 63;
    int n = lane & 15, quad = lane >> 4;
    int r0 = blockIdx.x * 128 + wave * 16;
    int node = r0 + n;
    int nc = (node < NN) ? node : (NN - 1);

    float acc[4][8];
#pragma unroll
    for (int ks = 0; ks < 4; ++ks)
#pragma unroll
        for (int c = 0; c < 8; ++c) acc[ks][c] = 0.f;
    float sw0 = 0.f, sw1 = 0.f, sw2 = 0.f, sw3 = 0.f;

    // x0 self-term loads
    unsigned xs4 = *(const unsigned*)&x0sc[(size_t)nc * 4];
    const unsigned char* xb = x08 + (size_t)nc * 128 + quad * 16;
    uint4 xa = *(const uint4*)xb;
    uint4 xc = *(const uint4*)(xb + 64);

    int s = 0, e = 0;
    if (node < NN) { s = rp[node]; e = rp[node + 1]; }
    int cnt = e - s;
    int npairs = cnt >> 1;

    const unsigned char* hb = hin8 + quad * 16;

    int2 cP0, cP1, fP0, fP1;
    unsigned cS0, cS1;
    uint4 cA0, cB0, cA1, cB1;
    if (npairs > 0) {
        cP0 = ep[s]; cP1 = ep[s + 1];
        cS0 = *(const unsigned*)&hinsc[(size_t)cP0.x * 4];
        cS1 = *(const unsigned*)&hinsc[(size_t)cP1.x * 4];
        const unsigned char* b0 = hb + (size_t)cP0.x * 128;
        const unsigned char* b1 = hb + (size_t)cP1.x * 128;
        cA0 = *(const uint4*)b0; cB0 = *(const uint4*)(b0 + 64);
        cA1 = *(const uint4*)b1; cB1 = *(const uint4*)(b1 + 64);
        int jf = s + 2; if (jf > EE - 2) jf = EE - 2;
        fP0 = ep[jf]; fP1 = ep[jf + 1];
    }

    EDGE_FMA(xs4, 0.1f, xa, xc);   // weight 0.1 on x0 (alpha mix)

    int j = s;
    for (int it = 0; it < npairs; ++it) {
        int j2 = j + 4; if (j2 > EE - 2) j2 = EE - 2;
        int2 eN0 = ep[j2], eN1 = ep[j2 + 1];
        unsigned tS0 = *(const unsigned*)&hinsc[(size_t)fP0.x * 4];
        unsigned tS1 = *(const unsigned*)&hinsc[(size_t)fP1.x * 4];
        const unsigned char* b0 = hb + (size_t)fP0.x * 128;
        const unsigned char* b1 = hb + (size_t)fP1.x * 128;
        uint4 tA0 = *(const uint4*)b0, tB0 = *(const uint4*)(b0 + 64);
        uint4 tA1 = *(const uint4*)b1, tB1 = *(const uint4*)(b1 + 64);
        EDGE_FMA(cS0, __int_as_float(cP0.y), cA0, cB0);
        EDGE_FMA(cS1, __int_as_float(cP1.y), cA1, cB1);
        cP0 = fP0; cP1 = fP1; fP0 = eN0; fP1 = eN1;
        cS0 = tS0; cS1 = tS1;
        cA0 = tA0; cB0 = tB0; cA1 = tA1; cB1 = tB1;
        j += 2;
    }
    if (cnt & 1) {
        int2 pe = ep[e - 1];
        unsigned s4 = *(const unsigned*)&hinsc[(size_t)pe.x * 4];
        const unsigned char* bp = hb + (size_t)pe.x * 128;
        uint4 ra = *(const uint4*)bp, rb = *(const uint4*)(bp + 64);
        EDGE_FMA(s4, __int_as_float(pe.y), ra, rb);
    }

    // bias correction (u8 -> u8-128) + bf16 A fragments
    bf16x8 av[4];
    {
        float sws[4] = {sw0, sw1, sw2, sw3};
#pragma unroll
        for (int ks = 0; ks < 4; ++ks)
#pragma unroll
            for (int c = 0; c < 8; ++c)
                av[ks][c] = (__bf16)(acc[ks][c] - 128.0f * sws[ks]);
    }

    __syncthreads();  // Bs staging complete across all waves

    f32x4 gacc[8];
#pragma unroll
    for (int t = 0; t < 8; ++t) gacc[t] = (f32x4){0.f, 0.f, 0.f, 0.f};

#pragma unroll
    for (int ks = 0; ks < 4; ++ks) {
#pragma unroll
        for (int t = 0; t < 8; ++t) {
            int base = ((t * 4 + ks) * 64 + lane) * 8;
            bf16x8 bh = *(const bf16x8*)&Bs[base];
            bf16x8 bl = *(const bf16x8*)&Bs[DH * DH + base];
            gacc[t] = MFMA(av[ks], bh, gacc[t]);
            gacc[t] = MFMA(av[ks], bl, gacc[t]);
        }
    }

#pragma unroll
    for (int t = 0; t < 8; ++t) {
        float sm = 0.f, qq = 0.f;
#pragma unroll
        for (int r = 0; r < 4; ++r) {
            int row = r0 + quad * 4 + r;
            float v = gacc[t][r];
            if (row < NN) {
                aout[(size_t)row * DH + t * 16 + n] = (__bf16)v;
                sm += v;
                qq += v * v;
            }
        }
        sm += __shfl_xor(sm, 16); sm += __shfl_xor(sm, 32);
        qq += __shfl_xor(qq, 16); qq += __shfl_xor(qq, 32);
        if (quad == 0) {
            red[0][wave][t * 16 + n] = sm;
            red[1][wave][t * 16 + n] = qq;
        }
    }
    __syncthreads();
    if (tid < 256) {
        int which = tid >> 7, jj = tid & 127;
        float tot = 0.f;
#pragma unroll
        for (int w = 0; w < 8; ++w) tot += red[which][w][jj];
        atomicAdd(&stats32[(size_t)(blockIdx.x & (NSLOT - 1)) * 256 + tid], tot);
    }
}

// ---------------- input GEMM + fused int8 encode: x0/x08/xsc from X[perm[i]] ----------------
__global__ __launch_bounds__(512, 4) void k_lin_in(const float* __restrict__ X, const int* __restrict__ perm,
                                                   const __bf16* __restrict__ Bhi, const __bf16* __restrict__ Blo,
                                                   const float* __restrict__ bin, __bf16* __restrict__ x0,
                                                   unsigned char* __restrict__ x08, unsigned char* __restrict__ xsc) {
    __shared__ __bf16 Bs[2 * DH * DH];
    int tid = threadIdx.x;
    {
        const f32x4* sh = (const f32x4*)Bhi;
        const f32x4* sl = (const f32x4*)Blo;
        f32x4* dh = (f32x4*)Bs;
        f32x4* dl = (f32x4*)(Bs + DH * DH);
#pragma unroll
        for (int i = 0; i < 4; ++i) {
            dh[tid + i * 512] = sh[tid + i * 512];
            dl[tid + i * 512] = sl[tid + i * 512];
        }
    }
    __syncthreads();

    int wave = tid >> 6, lane = tid & 63;
    int n = lane & 15, quad = lane >> 4;
    int r0 = blockIdx.x * 128 + wave * 16;
    int arow = r0 + n;
    if (arow > NN - 1) arow = NN - 1;
    const float* pa = X + (size_t)perm[arow] * DH + quad * 8;

    f32x4 acc[8];
#pragma unroll
    for (int t = 0; t < 8; ++t) acc[t] = (f32x4){0.f, 0.f, 0.f, 0.f};

#pragma unroll
    for (int ks = 0; ks < 4; ++ks) {
        bf16x8 ah, al;
        split8(pa + ks * 32, ah, al);
#pragma unroll
        for (int t = 0; t < 8; ++t) {
            int base = ((t * 4 + ks) * 64 + lane) * 8;
            bf16x8 bh = *(const bf16x8*)&Bs[base];
            bf16x8 bl = *(const bf16x8*)&Bs[DH * DH + base];
            acc[t] = MFMA(ah, bh, acc[t]);
            acc[t] = MFMA(al, bh, acc[t]);
            acc[t] = MFMA(ah, bl, acc[t]);
        }
    }

#pragma unroll
    for (int t = 0; t < 8; ++t) {
        float bj = bin[t * 16 + n];
#pragma unroll
        for (int r = 0; r < 4; ++r) {
            float v = fmaxf(acc[t][r] + bj, 0.f);
            acc[t][r] = v;
            int row = r0 + quad * 4 + r;
            if (row < NN) x0[(size_t)row * DH + t * 16 + n] = (__bf16)v;
        }
    }

    // fused int8 encode (bf16 rounding first to match the reference rounding point)
    float m[4][4];
#pragma unroll
    for (int r = 0; r < 4; ++r)
#pragma unroll
        for (int g = 0; g < 4; ++g) {
            float v0 = (float)(__bf16)acc[2 * g][r];
            float v1 = (float)(__bf16)acc[2 * g + 1][r];
            m[r][g] = fmaxf(fabsf(v0), fabsf(v1));
        }
#pragma unroll
    for (int d = 1; d <= 8; d <<= 1)
#pragma unroll
        for (int r = 0; r < 4; ++r)
#pragma unroll
            for (int g = 0; g < 4; ++g)
                m[r][g] = fmaxf(m[r][g], __shfl_xor(m[r][g], d));
    unsigned ebu[4];
    float sinv[4][4];
#pragma unroll
    for (int r = 0; r < 4; ++r) {
        unsigned u32 = 0;
#pragma unroll
        for (int g = 0; g < 4; ++g) {
            unsigned em = (__float_as_uint(m[r][g]) >> 23) & 0xffu;
            unsigned eb;
            float si;
            if (em < 7) { eb = 0; si = 0.f; }
            else { eb = em - 6; si = __uint_as_float((254 - eb) << 23); }
            u32 |= eb << (8 * g);
            sinv[r][g] = si;
        }
        ebu[r] = u32;
    }
#pragma unroll
    for (int t = 0; t < 8; ++t) {
        int wb = (t >> 2) * 64 + ((((t & 1) << 1) | (n >> 3))) * 16 + ((t >> 1) & 1) * 8 + (n & 7);
#pragma unroll
        for (int r = 0; r < 4; ++r) {
            int row = r0 + quad * 4 + r;
            if (row < NN) {
                float v = (float)(__bf16)acc[t][r];
                unsigned qv = (unsigned)rintf(fminf(fmaf(v, sinv[r][t >> 1], 128.f), 255.f));
                x08[(size_t)row * 128 + wb] = (unsigned char)qv;
            }
        }
    }
    if (n == 0) {
#pragma unroll
        for (int r = 0; r < 4; ++r) {
            int row = r0 + quad * 4 + r;
            if (row < NN) *(unsigned*)&xsc[(size_t)row * 4] = ebu[r];
        }
    }
}

// ---------------- output GEMM: out[perm[i]] = h[i] @ Wout + bout (512 threads) ----------------
__global__ __launch_bounds__(512, 4) void k_gemm_out(const __bf16* __restrict__ A, const int* __restrict__ perm,
                                                     const __bf16* __restrict__ Bhi, const __bf16* __restrict__ Blo,
                                                     const float* __restrict__ bout, float* __restrict__ out) {
    __shared__ __bf16 Bs[2 * 48 * DH];
    int tid = threadIdx.x;
    {
        // 48*DH bf16 = 768 f32x4 per half; 512 threads -> 2 guarded passes
        // (R12 bug: single `tid<384` pass staged only half -> NaN)
        const f32x4* sh = (const f32x4*)Bhi;
        const f32x4* sl = (const f32x4*)Blo;
        f32x4* dh = (f32x4*)Bs;
        f32x4* dl = (f32x4*)(Bs + 48 * DH);
#pragma unroll
        for (int i = 0; i < 2; ++i) {
            int idx = tid + i * 512;
            if (idx < 768) {
                dh[idx] = sh[idx];
                dl[idx] = sl[idx];
            }
        }
    }
    __syncthreads();

    int wave = tid >> 6, lane = tid & 63;
    int n = lane & 15, quad = lane >> 4;
    int r0 = blockIdx.x * 128 + wave * 16;
    int arow = r0 + n;
    if (arow > NN - 1) arow = NN - 1;
    const __bf16* pa = A + (size_t)arow * DH + quad * 8;

    f32x4 acc[3];
#pragma unroll
    for (int t = 0; t < 3; ++t) acc[t] = (f32x4){0.f, 0.f, 0.f, 0.f};

#pragma unroll
    for (int ks = 0; ks < 4; ++ks) {
        bf16x8 av = *(const bf16x8*)(pa + ks * 32);
#pragma unroll
        for (int t = 0; t < 3; ++t) {
            int base = ((t * 4 + ks) * 64 + lane) * 8;
            bf16x8 bh = *(const bf16x8*)&Bs[base];
            bf16x8 bl = *(const bf16x8*)&Bs[48 * DH + base];
            acc[t] = MFMA(av, bh, acc[t]);
            acc[t] = MFMA(av, bl, acc[t]);
        }
    }

    int prow[4];
#pragma unroll
    for (int r = 0; r < 4; ++r) {
        int row = r0 + quad * 4 + r;
        prow[r] = (row < NN) ? perm[row] : 0;
    }

#pragma unroll
    for (int t = 0; t < 3; ++t) {
        int j = t * 16 + n;
        float bj = (j < 40) ? bout[j] : 0.f;
#pragma unroll
        for (int r = 0; r < 4; ++r) {
            int row = r0 + quad * 4 + r;
            if (row < NN && j < 40) out[(size_t)prow[r] * 40 + j] = acc[t][r] + bj;
        }
    }
}

// ---------------- fused slot-reduce + BN-finalize + update + int8 re-encode (bf16 a input) ----------------
__global__ __launch_bounds__(256) void k_update(const __bf16* __restrict__ a, const __bf16* __restrict__ hin,
                                                __bf16* __restrict__ hout,
                                                unsigned char* __restrict__ h8, unsigned char* __restrict__ hsc,
                                                const float* __restrict__ stats32,
                                                const float* __restrict__ gamma, const float* __restrict__ bbeta) {
    __shared__ float scb[DH], shb[DH];
    int tid = threadIdx.x;
    if (tid < DH) {
        float s = 0.f, q = 0.f;
#pragma unroll
        for (int sl = 0; sl < NSLOT; ++sl) {
            s += stats32[(size_t)sl * 256 + tid];
            q += stats32[(size_t)sl * 256 + 128 + tid];
        }
        float mu = s * (1.0f / NN);
        float var = q * (1.0f / NN) - mu * mu;
        if (var < 0.f) var = 0.f;
        float sc = gamma[tid] * rsqrtf(var + 1e-5f);
        scb[tid] = sc;
        shb[tid] = bbeta[tid] - mu * sc;
    }
    __syncthreads();

    int idx = blockIdx.x * 256 + tid;
    int sub = idx & 15;
    int j0 = sub * 8;
    bf16x8 av = ((const bf16x8*)a)[idx];
    bf16x8 hv = ((const bf16x8*)hin)[idx];
    bf16x8 o;
    float vv[8];
    float mx = 0.f;
#pragma unroll
    for (int c = 0; c < 8; ++c) {
        int j = j0 + c;
        float v = fmaxf(fmaf((float)av[c], scb[j], shb[j]) + (float)hv[c], 0.f);
        vv[c] = v;
        mx = fmaxf(mx, v);          // relu'd: v >= 0
        o[c] = (__bf16)v;
    }
    ((bf16x8*)hout)[idx] = o;

    // group max across the 4 threads sharing cols [ks*32, ks*32+32)
    mx = fmaxf(mx, __shfl_xor(mx, 1));
    mx = fmaxf(mx, __shfl_xor(mx, 2));
    unsigned int em = (__float_as_uint(mx) >> 23) & 0xffu;
    unsigned int eb;
    float sinv;
    if (em < 7) { eb = 0; sinv = 0.f; }
    else { eb = em - 6; sinv = __uint_as_float((254 - eb) << 23); }
    if ((tid & 3) == 0) hsc[(size_t)(idx >> 4) * 4 + (sub >> 2)] = (unsigned char)eb;
    uint2 pk;
    pk.x = 0; pk.y = 0;
#pragma unroll
    for (int c = 0; c < 4; ++c) {
        unsigned int q0 = (unsigned int)rintf(fminf(fmaf(vv[c], sinv, 128.f), 255.f));
        unsigned int q1 = (unsigned int)rintf(fminf(fmaf(vv[4 + c], sinv, 128.f), 255.f));
        pk.x |= q0 << (8 * c);
        pk.y |= q1 << (8 * c);
    }
    // fragment-contiguous position: P = (ks>>1)*64 + q*16 + (ks&1)*8, ks=sub>>2, q=sub&3
    unsigned wpos = ((sub >> 3) & 1) * 64 + (sub & 3) * 16 + ((sub >> 2) & 1) * 8;
    *(uint2*)&h8[(size_t)(idx >> 4) * 128 + wpos] = pk;
}

extern "C" void kernel_launch(void* const* d_in, const int* in_sizes, int n_in,
                              void* d_out, int out_size, void* d_ws, size_t ws_size,
                              hipStream_t stream) {
    const float* x = (const float*)d_in[0];
    const float* ew = (const float*)d_in[1];
    const float* Win = (const float*)d_in[2];
    const float* bin = (const float*)d_in[3];
    const float* convW = (const float*)d_in[4];
    const float* gamma = (const float*)d_in[5];
    const float* bbeta = (const float*)d_in[6];
    const float* Wout = (const float*)d_in[7];
    const float* bout = (const float*)d_in[8];
    const int* erow = (const int*)d_in[9];
    const int* ecol = (const int*)d_in[10];
    float* out = (float*)d_out;

    char* wsp = (char*)d_ws;
    size_t off = 0;
    auto alloc = [&](size_t bytes) -> void* {
        void* p = wsp + off;
        off += (bytes + 255) & ~(size_t)255;
        return p;
    };
    __bf16* x0 = (__bf16*)alloc((size_t)NN * DH * 2);
    __bf16* h = (__bf16*)alloc((size_t)NN * DH * 2);
    __bf16* a = (__bf16*)alloc((size_t)NN * DH * 2);
    unsigned char* x08 = (unsigned char*)alloc((size_t)NN * DH);
    unsigned char* h8 = (unsigned char*)alloc((size_t)NN * DH);
    unsigned char* x0sc = (unsigned char*)alloc((size_t)NN * 4);
    unsigned char* hsc = (unsigned char*)alloc((size_t)NN * 4);
    int* rp = (int*)alloc((NN + 1) * 4);
    int* perm = (int*)alloc((size_t)NN * 4);
    int* iperm = (int*)alloc((size_t)NN * 4);
    int* cnt2 = (int*)alloc((size_t)NN * 4);
    int* dpre = (int*)alloc(64 * 4);
    // zero-init region: cnt | fil | stats32 | dbin | dfil as ONE memset
    size_t zero_bytes = (size_t)NN * 4 + (size_t)NN * 4 + (size_t)NL * NSLOT * 256 * 4 + 128 * 4;
    int* cnt = (int*)alloc(zero_bytes);
    int* fil = cnt + NN;
    float* stats32 = (float*)(fil + NN);
    int* dbin = (int*)(stats32 + (size_t)NL * NSLOT * 256);
    int* dfil = dbin + 64;
    int2* ep = (int2*)alloc((size_t)EE * 8);
    int* part = (int*)alloc(256 * 4);
    __bf16* Bhi = (__bf16*)alloc((size_t)(NL + 1) * DH * DH * 2);
    __bf16* Blo = (__bf16*)alloc((size_t)(NL + 1) * DH * DH * 2);
    __bf16* Bohi = (__bf16*)alloc((size_t)DH * 48 * 2);
    __bf16* Bolo = (__bf16*)alloc((size_t)DH * 48 * 2);

    hipMemsetAsync(cnt, 0, zero_bytes, stream);

    k_hist<<<3125, 256, 0, stream>>>(erow, cnt);
    k_dhist<<<391, 256, 0, stream>>>(cnt, dbin);
    k_pscan<<<1, 64, 0, stream>>>(dbin, dpre);
    k_pscatter<<<391, 256, 0, stream>>>(cnt, dpre, dfil, perm);
    k_iperm<<<391, 256, 0, stream>>>(perm, cnt, iperm, cnt2);
    k_scan1<<<196, 512, 0, stream>>>(cnt2, rp, part);
    k_scan2<<<1, 256, 0, stream>>>(part, 196);
    k_scan3<<<196, 512, 0, stream>>>(rp, part);
    k_fill<<<3125, 256, 0, stream>>>(erow, ecol, ew, rp, iperm, fil, ep);

    k_prep_w<<<NL + 1, 256, 0, stream>>>(convW, Win, Bhi, Blo);
    k_prep_out<<<1, 256, 0, stream>>>(Wout, Bohi, Bolo);

    k_lin_in<<<SG_GRID, 512, 0, stream>>>(x, perm, Bhi + (size_t)NL * DH * DH, Blo + (size_t)NL * DH * DH,
                                          bin, x0, x08, x0sc);

    for (int l = 0; l < NL; ++l) {
        const unsigned char* hin8 = (l == 0) ? x08 : h8;
        const unsigned char* hinsc = (l == 0) ? x0sc : hsc;
        const __bf16* hin = (l == 0) ? x0 : h;
        float* st = stats32 + (size_t)l * NSLOT * 256;
        k_spmm_gemm<<<SG_GRID, 512, 0, stream>>>(hin8, hinsc, x08, x0sc, rp, ep, a,
                                                 Bhi + (size_t)l * DH * DH, Blo + (size_t)l * DH * DH, st);
        k_update<<<6250, 256, 0, stream>>>(a, hin, h, h8, hsc, st, gamma + l * DH, bbeta + l * DH);
    }
    k_gemm_out<<<SG_GRID, 512, 0, stream>>>(h, perm, Bohi, Bolo, bout, out);
}